// Round 14
// baseline (578.553 us; speedup 1.0000x reference)
//
#include <hip/hip_runtime.h>
#include <hip/hip_bf16.h>

#define NUM_OPS   100000
#define NUM_MACH  512
#define HDIM      128
#define P1        100352            // m2o key offset (98*1024)
#define NHIST     200704            // 196*1024 == 784*256 combined key space
#define NBLK      196               // op-hist scan blocks (1024 elems each)
#define NCOARSE   784               // coarse buckets (key >> 8)
#define NBC       256               // blocks for coarse hist/fill passes
#define NBM       256               // counting-sort blocks for machine buckets
#define MHWORDS   (NUM_MACH * NBM)  // 131072 = 128*1024
#define NBLK_M    128               // machine blockhist scan blocks
#define NBLK_T    (NBLK + NBLK_M)   // 324 unified scan blocks
#define NMB       (NUM_MACH * 8)    // 4096 machine-gather blocks (placed FIRST in grid)

typedef short short8 __attribute__((ext_vector_type(8)));
typedef unsigned short ushort8 __attribute__((ext_vector_type(8)));
typedef float floatx4 __attribute__((ext_vector_type(4)));

__device__ __forceinline__ unsigned short f2bf(float f) {
    unsigned u = __float_as_uint(f);
    unsigned r = (u + 0x7FFFu + ((u >> 16) & 1u)) >> 16;   // RNE
    return (unsigned short)r;
}
__device__ __forceinline__ float bf2f(unsigned short u) {
    return __uint_as_float(((unsigned)u) << 16);
}

// ---------------- prep: op embed (bf16) | mach embed (+bf16) | weights | mach_sum zero --------
__global__ void k_prep(const float* __restrict__ Fo, const float* __restrict__ Fm,
                       const float* __restrict__ Wo, const float* __restrict__ bo,
                       const float* __restrict__ Wm, const float* __restrict__ bm,
                       const float* __restrict__ Wp, const float* __restrict__ Wc,
                       unsigned short* __restrict__ op_ebf,
                       float* __restrict__ mach_emb, unsigned short* __restrict__ mach_ebf,
                       unsigned short* __restrict__ Wb, float* __restrict__ mach_sum) {
    int idx = blockIdx.x * blockDim.x + threadIdx.x;
    if (idx < NUM_OPS * HDIM) {
        int r = idx >> 7, h = idx & 127;
        const float* f = Fo + (size_t)r * 6;
        const float* w = Wo + (size_t)h * 6;
        float s = bo[h];
#pragma unroll
        for (int i = 0; i < 6; ++i) s += f[i] * w[i];
        op_ebf[idx] = f2bf(s);
        return;
    }
    idx -= NUM_OPS * HDIM;
    if (idx < NUM_MACH * HDIM) {
        int r = idx >> 7, h = idx & 127;
        const float* f = Fm + (size_t)r * 2;
        const float* w = Wm + (size_t)h * 2;
        float s = bm[h] + f[0] * w[0] + f[1] * w[1];
        mach_emb[idx] = s;
        mach_ebf[idx] = f2bf(s);
        return;
    }
    idx -= NUM_MACH * HDIM;
    if (idx < 2 * 128 * 256) {
        int l = idx >> 15, h = (idx >> 8) & 127, k = idx & 255;
        float v = (k < 128) ? Wp[(size_t)l * 16384 + h * 128 + k]
                            : Wc[(size_t)l * 16384 + h * 128 + (k - 128)];
        Wb[idx] = f2bf(v);
        return;
    }
    idx -= 2 * 128 * 256;
    if (idx < NUM_MACH * HDIM) mach_sum[idx] = 0.f;
}

// ---------------- front: coarse op-key histogram + machine histogram (shared comp_e read) ----
__global__ __launch_bounds__(256) void k_front(const int* __restrict__ prec_e, int nprec,
                                               const int* __restrict__ comp_e, int E, int M,
                                               int* __restrict__ chist_bh,   // [784][256]
                                               int* __restrict__ mach_bh) {  // [512][256]
    __shared__ int hc[NCOARSE];
    __shared__ int hm[NUM_MACH];
    for (int i = threadIdx.x; i < NCOARSE; i += 256) hc[i] = 0;
    for (int i = threadIdx.x; i < NUM_MACH; i += 256) hm[i] = 0;
    __syncthreads();
    int NT = nprec + E;
    int ch = (NT + NBC - 1) / NBC;
    int i0 = blockIdx.x * ch, i1 = min(NT, i0 + ch);
    for (int i = i0 + threadIdx.x; i < i1; i += 256) {
        int key;
        if (i < nprec) key = prec_e[nprec + i];
        else {
            int e = i - nprec;
            key = P1 + comp_e[e];
            atomicAdd(&hm[comp_e[E + e] - M], 1);
        }
        atomicAdd(&hc[key >> 8], 1);
    }
    __syncthreads();
    for (int i = threadIdx.x; i < NCOARSE; i += 256)
        chist_bh[i * NBC + blockIdx.x] = hc[i];
    for (int i = threadIdx.x; i < NUM_MACH; i += 256)
        mach_bh[i * NBC + blockIdx.x] = hm[i];
}

// ---------------- coarse pass B: place packed (val<<8 | key&255) via LDS cursors ----------------
__global__ __launch_bounds__(256) void k_cfill(const int* __restrict__ prec_e, int nprec,
                                               const int* __restrict__ comp_e, int E, int M,
                                               const int* __restrict__ scan,
                                               int* __restrict__ pairs) {
    __shared__ int cur[NCOARSE];
    for (int i = threadIdx.x; i < NCOARSE; i += 256) cur[i] = scan[i * NBC + blockIdx.x];
    __syncthreads();
    int NT = nprec + E;
    int ch = (NT + NBC - 1) / NBC;
    int i0 = blockIdx.x * ch, i1 = min(NT, i0 + ch);
    for (int i = i0 + threadIdx.x; i < i1; i += 256) {
        int key, val;
        if (i < nprec) { key = prec_e[nprec + i]; val = prec_e[i]; }
        else { int e = i - nprec; key = P1 + comp_e[e]; val = comp_e[E + e] - M; }
        int pos = atomicAdd(&cur[key >> 8], 1);
        pairs[pos] = (val << 8) | (key & 255);
    }
}

// ---------------- scan phase 1: per-block sums over unified [chist|mach_bh] ----------------
__global__ __launch_bounds__(256) void k_blocksum(const int* __restrict__ arr, int* __restrict__ partial) {
    __shared__ int sh[256];
    int b = blockIdx.x, t = threadIdx.x;
    int4 v = *(const int4*)(arr + b * 1024 + t * 4);
    sh[t] = v.x + v.y + v.z + v.w;
    __syncthreads();
    for (int o = 128; o; o >>= 1) { if (t < o) sh[t] += sh[t + o]; __syncthreads(); }
    if (!t) partial[b] = sh[0];
}

// ---------------- scan phase 2: two independent segments (op: 196, machine: 128) --------------
__global__ __launch_bounds__(256) void k_scanpart(const int* __restrict__ partial,
                                                  int* __restrict__ block_off) {
    __shared__ int sh[256];
    int t = threadIdx.x;
    int seg0 = blockIdx.x ? NBLK : 0;
    int n    = blockIdx.x ? NBLK_M : NBLK;
    int v = (t < n) ? partial[seg0 + t] : 0;
    sh[t] = v; __syncthreads();
    for (int o = 1; o < 256; o <<= 1) {
        int x = (t >= o) ? sh[t - o] : 0; __syncthreads();
        sh[t] += x; __syncthreads();
    }
    if (t < n) block_off[seg0 + t] = sh[t] - v;
}

// ---------------- scan phase 3: write exclusive offsets (unified) ----------------
__global__ __launch_bounds__(256) void k_scanwrite(const int* __restrict__ arr,
                                                   const int* __restrict__ block_off,
                                                   int* __restrict__ rs) {
    __shared__ int sh[256];
    int b = blockIdx.x, t = threadIdx.x;
    int base_i = b * 1024 + t * 4;
    int4 v = *(const int4*)(arr + base_i);
    int tsum = v.x + v.y + v.z + v.w;
    sh[t] = tsum; __syncthreads();
    for (int o = 1; o < 256; o <<= 1) {
        int x = (t >= o) ? sh[t - o] : 0; __syncthreads();
        sh[t] += x; __syncthreads();
    }
    int off = block_off[b] + sh[t] - tsum;
    int4 r; r.x = off; r.y = off + v.x; r.z = off + v.x + v.y; r.w = off + v.x + v.y + v.z;
    *(int4*)(rs + base_i) = r;
}

// ---------------- fine counting sort (op keys) + machine placement + mach_rs, one launch -----
__global__ __launch_bounds__(256) void k_finefill(const int* __restrict__ scans, int NT,
                                                  const int* __restrict__ pairs,
                                                  int* __restrict__ rs,
                                                  int* __restrict__ bucket_all,
                                                  const int* __restrict__ comp_e, int E, int M,
                                                  int* __restrict__ bucket_mach,
                                                  int* __restrict__ mach_rs) {
    int t = threadIdx.x;
    if (blockIdx.x < NCOARSE) {
        __shared__ int hh[256];
        __shared__ int ex[256];
        __shared__ int cu[256];
        int b = blockIdx.x;
        int s = scans[b * NBC];
        int e = (b == NCOARSE - 1) ? NT : scans[(b + 1) * NBC];
        hh[t] = 0;
        __syncthreads();
        for (int i = s + t; i < e; i += 256) atomicAdd(&hh[pairs[i] & 255], 1);
        __syncthreads();
        int v = hh[t];
        ex[t] = v; __syncthreads();
        for (int o = 1; o < 256; o <<= 1) {
            int x = (t >= o) ? ex[t - o] : 0; __syncthreads();
            ex[t] += x; __syncthreads();
        }
        int start = s + ex[t] - v;
        rs[b * 256 + t] = start;
        cu[t] = start;
        __syncthreads();
        for (int i = s + t; i < e; i += 256) {
            int p = pairs[i];
            int pos = atomicAdd(&cu[p & 255], 1);
            bucket_all[pos] = ((unsigned)p) >> 8;
        }
    } else {
        __shared__ int cur[NUM_MACH];
        int blk = blockIdx.x - NCOARSE;
        const int* moff = scans + NHIST;
        for (int i = t; i < NUM_MACH; i += 256) cur[i] = moff[i * NBM + blk];
        if (blk == 0) {
            for (int m = t; m < NUM_MACH; m += 256) mach_rs[m] = moff[m * NBM];
            if (t == 0) mach_rs[NUM_MACH] = E;
        }
        __syncthreads();
        int nprec = NT - E;
        int chNT = (NT + NBC - 1) / NBC;            // SAME chunking as k_front
        int e0 = blk * chNT - nprec;       if (e0 < 0) e0 = 0;
        int e1 = (blk + 1) * chNT - nprec; if (e1 > E) e1 = E;
        for (int e = e0 + t; e < e1; e += 256) {
            int m = comp_e[E + e] - M;
            int op = comp_e[e];
            int pos = atomicAdd(&cur[m], 1);
            bucket_mach[pos] = op;
        }
    }
}

#define ACC8(acc, v) { _Pragma("unroll") for (int k = 0; k < 8; ++k) acc[k] += bf2f((unsigned short)v[k]); }

// ---------------- merged per-layer aggregation: machine gather FIRST | op-side gather->Ab -----
// Machine-gather blocks occupy IDs [0, NMB): long-running waves start at t=0 and overlap the
// agg swarm (r13: they were at the grid tail -> low-occupancy drain). 8 blocks/machine = 32
// groups of ~48 edges each. Op-agg blocks at IDs >= NMB (r9-verified dual-stream config).
__global__ __launch_bounds__(256) void k_aggmg(
    const unsigned short* __restrict__ op_ebf, const unsigned short* __restrict__ mach_ebf,
    const int* __restrict__ rs, const int* __restrict__ bucket_all,
    unsigned short* __restrict__ Ab, int* __restrict__ flags, int M,
    const int* __restrict__ mach_rs, const int* __restrict__ bucket_mach,
    float* __restrict__ mach_sum) {
    int wave = threadIdx.x >> 6, lane = threadIdx.x & 63;
    int g = lane >> 4;               // edge sub-group 0..3
    int d = (lane & 15) * 8;         // dim base: 8 bf16 per lane

    if ((int)blockIdx.x < NMB) {
        // ---- machine gather: 16-edge staged batches, 32 groups/machine, stride 2048 ----
        int m  = blockIdx.x & 511;
        int yq = blockIdx.x >> 9;         // 0..7
        int s0 = mach_rs[m], e0 = mach_rs[m + 1];
        float a[8];
#pragma unroll
        for (int k = 0; k < 8; ++k) a[k] = 0.f;

        for (int base = s0 + (yq * 4 + wave) * 64; base < e0; base += 2048) {
            int cnt = min(64, e0 - base);
            int idx = (lane < cnt) ? bucket_mach[base + lane] : 0;
            int j = 0;
            for (; j + 16 <= cnt; j += 16) {
                int r0 = __shfl(idx, j + g);
                int r1 = __shfl(idx, j + 4 + g);
                int r2 = __shfl(idx, j + 8 + g);
                int r3 = __shfl(idx, j + 12 + g);
                short8 v0 = *(const short8*)(op_ebf + (size_t)r0 * HDIM + d);
                short8 v1 = *(const short8*)(op_ebf + (size_t)r1 * HDIM + d);
                short8 v2 = *(const short8*)(op_ebf + (size_t)r2 * HDIM + d);
                short8 v3 = *(const short8*)(op_ebf + (size_t)r3 * HDIM + d);
                ACC8(a, v0); ACC8(a, v1); ACC8(a, v2); ACC8(a, v3);
            }
            for (; j < cnt; j += 4) {
                int jj = j + g;
                int rowi = __shfl(idx, jj);
                short8 v = *(const short8*)(op_ebf + (size_t)rowi * HDIM + d);
                if (jj < cnt) ACC8(a, v);
            }
        }
#pragma unroll
        for (int k = 0; k < 8; ++k) {
            a[k] += __shfl_xor(a[k], 16);
            a[k] += __shfl_xor(a[k], 32);
        }
        if (lane < 16) {
#pragma unroll
            for (int k = 0; k < 8; ++k)
                atomicAdd(&mach_sum[m * HDIM + d + k], a[k]);
        }
        return;
    }

    // ---- op aggregation: dual-stream interleaved gather (4 loads in flight) ----
    int r = (blockIdx.x - NMB) * 4 + wave;
    if (r >= M) return;
    int sA = rs[r],      eA = rs[r + 1];
    int sB = rs[P1 + r], eB = rs[P1 + r + 1];

    float a[8], b[8];
#pragma unroll
    for (int k = 0; k < 8; ++k) { a[k] = 0.f; b[k] = 0.f; }

    int baseA = sA, baseB = sB;
    while (baseA < eA || baseB < eB) {
        int cA = (baseA < eA) ? min(64, eA - baseA) : 0;
        int cB = (baseB < eB) ? min(64, eB - baseB) : 0;
        int idxA = (lane < cA) ? bucket_all[baseA + lane] : 0;
        int idxB = (lane < cB) ? bucket_all[baseB + lane] : 0;
        int jm = max(cA, cB);
        for (int j = 0; j < jm; j += 8) {
            int j0 = j + g, j1 = j + 4 + g;
            int rA0 = __shfl(idxA, j0);
            int rA1 = __shfl(idxA, j1);
            int rB0 = __shfl(idxB, j0);
            int rB1 = __shfl(idxB, j1);
            short8 vA0 = *(const short8*)(op_ebf   + (size_t)rA0 * HDIM + d);
            short8 vA1 = *(const short8*)(op_ebf   + (size_t)rA1 * HDIM + d);
            short8 vB0 = *(const short8*)(mach_ebf + (size_t)rB0 * HDIM + d);
            short8 vB1 = *(const short8*)(mach_ebf + (size_t)rB1 * HDIM + d);
            if (j0 < cA) ACC8(a, vA0);
            if (j1 < cA) ACC8(a, vA1);
            if (j0 < cB) ACC8(b, vB0);
            if (j1 < cB) ACC8(b, vB1);
        }
        baseA += 64; baseB += 64;
    }
#pragma unroll
    for (int k = 0; k < 8; ++k) {
        a[k] += __shfl_xor(a[k], 16);
        a[k] += __shfl_xor(a[k], 32);
        b[k] += __shfl_xor(b[k], 16);
        b[k] += __shfl_xor(b[k], 32);
    }
    float pinv = 1.f / fmaxf((float)(eA - sA), 1.f);
    float cinv = 1.f / fmaxf((float)(eB - sB), 1.f);

    if (lane < 16) {
        ushort8 pa, pb;
#pragma unroll
        for (int k = 0; k < 8; ++k) { pa[k] = f2bf(a[k] * pinv); pb[k] = f2bf(b[k] * cinv); }
        *(ushort8*)(Ab + (size_t)r * 256 + d)       = pa;
        *(ushort8*)(Ab + (size_t)r * 256 + 128 + d) = pb;
    }
    if (lane == 0) flags[r] = (eA > sA ? 1 : 0) | (eB > sB ? 2 : 0);
}

// ---------------- MFMA GEMM + bf16 residual + LN  |  machine update (tail blocks) ------------
// blocks [0, nb_gemm): op update. blocks [nb_gemm, +NUM_MACH): machine update + mach_sum zero.
__global__ __launch_bounds__(256) void k_gemm_mupd(
    const unsigned short* __restrict__ Ab, const unsigned short* __restrict__ embb,
    const unsigned short* __restrict__ Wb,
    const float* __restrict__ bp, const float* __restrict__ bc,
    const int* __restrict__ flags,
    const float* __restrict__ g, const float* __restrict__ bt,
    float* __restrict__ dstf, unsigned short* __restrict__ dstb, int M, int nb_gemm,
    const float* __restrict__ mach_emb, float* __restrict__ mach_sum,
    const int* __restrict__ mach_rs,
    const float* __restrict__ Wc,
    const float* __restrict__ gm, const float* __restrict__ btm,
    float* __restrict__ mdst, unsigned short* __restrict__ mdstb) {
    if ((int)blockIdx.x >= nb_gemm) {
        // ---- machine update: mean -> @Wc^T + bc -> +emb -> LN; zero mach_sum after read ----
        __shared__ float row[HDIM];
        __shared__ float red[4];
        int m = blockIdx.x - nb_gemm, t = threadIdx.x;
        int cnt = mach_rs[m + 1] - mach_rs[m];
        float sc = (cnt > 0) ? 1.f / (float)cnt : 0.f;
        if (t < HDIM) {
            row[t] = mach_sum[m * HDIM + t] * sc;
            mach_sum[m * HDIM + t] = 0.f;      // ready for next layer's atomics
        }
        __syncthreads();
        float x = 0.f, s = 0.f, q = 0.f;
        if (t < HDIM) {
            float dot = bc[t];
            const float* w = Wc + (size_t)t * HDIM;
#pragma unroll 8
            for (int k = 0; k < HDIM; ++k) dot += row[k] * w[k];
            x = mach_emb[m * HDIM + t] + ((cnt > 0) ? dot : 0.f);
            s = x; q = x * x;
#pragma unroll
            for (int o = 32; o; o >>= 1) { s += __shfl_xor(s, o); q += __shfl_xor(q, o); }
            int wv = t >> 6;
            if ((t & 63) == 0) { red[wv * 2] = s; red[wv * 2 + 1] = q; }
        }
        __syncthreads();
        if (t < HDIM) {
            s = red[0] + red[2]; q = red[1] + red[3];
            float mu = s * (1.f / 128.f);
            float rstd = rsqrtf(fmaxf(q * (1.f / 128.f) - mu * mu, 0.f) + 1e-5f);
            float y = (x - mu) * rstd * gm[t] + btm[t];
            mdst[m * HDIM + t] = y;
            if (mdstb) mdstb[m * HDIM + t] = f2bf(y);
        }
        return;
    }

    int wave = threadIdx.x >> 6, lane = threadIdx.x & 63;
    int m0 = blockIdx.x * 64 + wave * 16;
    if (m0 >= M) return;
    int quad = lane >> 4, col = lane & 15;

    floatx4 acc[8];
#pragma unroll
    for (int t = 0; t < 8; ++t) acc[t] = (floatx4){0.f, 0.f, 0.f, 0.f};

    const short* Arow  = (const short*)(Ab + (size_t)(m0 + col) * 256);
    const short* Wbase = (const short*)Wb;

#pragma unroll
    for (int ks = 0; ks < 8; ++ks) {
        short8 a = *(const short8*)(Arow + ks * 32 + quad * 8);
#pragma unroll
        for (int t = 0; t < 8; ++t) {
            short8 b = *(const short8*)(Wbase + (size_t)(t * 16 + col) * 256 + ks * 32 + quad * 8);
            acc[t] = __builtin_amdgcn_mfma_f32_16x16x32_bf16(a, b, acc[t], 0, 0, 0);
        }
    }

    float bpv[8], bcv[8], gv[8], btv[8];
#pragma unroll
    for (int t = 0; t < 8; ++t) {
        int c = t * 16 + col;
        bpv[t] = bp[c]; bcv[t] = bc[c]; gv[t] = g[c]; btv[t] = bt[c];
    }
#pragma unroll
    for (int reg = 0; reg < 4; ++reg) {
        int r = m0 + quad * 4 + reg;
        int fl = flags[r];
        float fp = (fl & 1) ? 1.f : 0.f, fc = (fl & 2) ? 1.f : 0.f;
        float x[8]; float s = 0.f, q = 0.f;
#pragma unroll
        for (int t = 0; t < 8; ++t) {
            float v = acc[t][reg] + bf2f(embb[(size_t)r * HDIM + t * 16 + col]) + fp * bpv[t] + fc * bcv[t];
            x[t] = v; s += v; q += v * v;
        }
#pragma unroll
        for (int msk = 1; msk < 16; msk <<= 1) { s += __shfl_xor(s, msk); q += __shfl_xor(q, msk); }
        float mu = s * (1.f / 128.f);
        float rstd = rsqrtf(fmaxf(q * (1.f / 128.f) - mu * mu, 0.f) + 1e-5f);
#pragma unroll
        for (int t = 0; t < 8; ++t) {
            float y = (x[t] - mu) * rstd * gv[t] + btv[t];
            if (dstf) dstf[(size_t)r * HDIM + t * 16 + col] = y;
            if (dstb) dstb[(size_t)r * HDIM + t * 16 + col] = f2bf(y);
        }
    }
}

extern "C" void kernel_launch(void* const* d_in, const int* in_sizes, int n_in,
                              void* d_out, int out_size, void* d_ws, size_t ws_size,
                              hipStream_t stream) {
    const float* op_feat    = (const float*)d_in[0];
    const float* m_feat     = (const float*)d_in[1];
    const int*   prec_e     = (const int*)d_in[2];
    const int*   comp_e     = (const int*)d_in[3];
    const float* op_emb_W   = (const float*)d_in[4];
    const float* op_emb_b   = (const float*)d_in[5];
    const float* mach_emb_W = (const float*)d_in[6];
    const float* mach_emb_b = (const float*)d_in[7];
    const float* prec_W     = (const float*)d_in[8];
    const float* prec_b     = (const float*)d_in[9];
    const float* compat_W   = (const float*)d_in[10];
    const float* compat_b   = (const float*)d_in[11];
    const float* op_ln_g    = (const float*)d_in[12];
    const float* op_ln_b    = (const float*)d_in[13];
    const float* mach_ln_g  = (const float*)d_in[14];
    const float* mach_ln_b  = (const float*)d_in[15];
    float* out = (float*)d_out;

    const int M = NUM_OPS, NM = NUM_MACH;
    const int nprec = in_sizes[2] / 2;
    const int ncomp = in_sizes[3] / 2;
    const int E = ncomp / 2;   // bidirectional pairs: first half o2m, second half m2o (mirror)
    const int NT = nprec + E;

    float* ws = (float*)d_ws;
    size_t o = 0;
    unsigned short* op_ebf = (unsigned short*)(ws + o); o += (size_t)M * 64;   // 25.6 MB bf16 state
    unsigned short* Ab = (unsigned short*)(ws + o); o += (size_t)M * 128;  // 51 MB bf16 [M][256]
    unsigned short* Wb = (unsigned short*)(ws + o); o += 32768;            // 2 layers x [128][256] bf16
    float* mach_emb = ws + o; o += (size_t)NM * HDIM;
    unsigned short* mach_ebf = (unsigned short*)(ws + o); o += (size_t)NM * 64;
    float* mach_sum = ws + o; o += (size_t)NM * HDIM;
    int* ip = (int*)(ws + o);
    size_t io = 0;
    int* hists     = ip + io; io += NHIST + MHWORDS;  // [chist 784x256 | mach_bh 512x256]
    int* scans     = ip + io; io += NHIST + MHWORDS;  // [cscan | moff] (exclusive offsets)
    int* rs        = ip + io; io += NHIST;            // fine row starts (exclusive)
    int* mach_rs   = ip + io; io += NM + 8;
    int* partialT  = ip + io; io += 512;              // unified block sums (324 used)
    int* block_off = ip + io; io += 512;
    int* flags     = ip + io; io += M;
    int* pairs     = ip + io; io += (size_t)NT;       // coarse-partitioned packed edges
    int* bucket_all  = ip + io; io += (size_t)NT;
    int* bucket_mach = ip + io; io += (size_t)E;

    int* mach_bh = hists + NHIST;

    // ---- CSR build: two-level counting sort, 6 launches ----
    k_front<<<NBC, 256, 0, stream>>>(prec_e, nprec, comp_e, E, M, hists, mach_bh);
    k_blocksum<<<NBLK_T, 256, 0, stream>>>(hists, partialT);
    k_scanpart<<<2, 256, 0, stream>>>(partialT, block_off);
    k_scanwrite<<<NBLK_T, 256, 0, stream>>>(hists, block_off, scans);
    k_cfill<<<NBC, 256, 0, stream>>>(prec_e, nprec, comp_e, E, M, scans, pairs);
    k_finefill<<<NCOARSE + NBM, 256, 0, stream>>>(scans, NT, pairs, rs, bucket_all,
                                                  comp_e, E, M, bucket_mach, mach_rs);

    // ---- embeddings + weight conversion + mach_sum zero, one launch ----
    int prep_total = (M + 2 * NM) * HDIM + 2 * 128 * 256;
    k_prep<<<(prep_total + 255) / 256, 256, 0, stream>>>(
        op_feat, m_feat, op_emb_W, op_emb_b, mach_emb_W, mach_emb_b,
        prec_W, compat_W, op_ebf, mach_emb, mach_ebf, Wb, mach_sum);

    const int nb_agg = (M + 3) / 4;      // 1 row per wave, 4 waves per block (r9 config)
    const int nb_gemm = (M + 63) / 64;
    for (int l = 0; l < 2; ++l) {
        int last = (l == 1);
        const float* bpl = prec_b   + (size_t)l * HDIM;
        const float* Wc  = compat_W + (size_t)l * HDIM * HDIM;
        const float* bcl = compat_b + (size_t)l * HDIM;

        // merged: machine gather (blocks 0..NMB-1, start first) + op aggregation (rest)
        k_aggmg<<<NMB + nb_agg, 256, 0, stream>>>(
            op_ebf, mach_ebf, rs, bucket_all, Ab, flags, M,
            mach_rs, bucket_mach, mach_sum);

        // merged: op update (MFMA+LN, in-place bf16 state) + machine update (zeroes mach_sum)
        k_gemm_mupd<<<nb_gemm + NM, 256, 0, stream>>>(
            Ab, op_ebf, Wb + (size_t)l * 128 * 256, bpl, bcl, flags,
            op_ln_g + (size_t)l * HDIM, op_ln_b + (size_t)l * HDIM,
            last ? out : nullptr, last ? nullptr : op_ebf, M, nb_gemm,
            mach_emb, mach_sum, mach_rs, Wc,
            mach_ln_g + (size_t)l * HDIM, mach_ln_b + (size_t)l * HDIM,
            last ? (out + (size_t)M * HDIM) : mach_emb, last ? nullptr : mach_ebf);
    }
}

// Round 15
// 521.298 us; speedup vs baseline: 1.1098x; 1.1098x over previous
//
#include <hip/hip_runtime.h>
#include <hip/hip_bf16.h>

#define NUM_OPS   100000
#define NUM_MACH  512
#define HDIM      128
#define P1        100352            // m2o key offset (98*1024)
#define NHIST     200704            // 196*1024 == 784*256 combined key space
#define NBLK      196               // op-hist scan blocks (1024 elems each)
#define NCOARSE   784               // coarse buckets (key >> 8)
#define NBC       256               // blocks for coarse hist/fill passes
#define NBM       256               // counting-sort blocks for machine buckets
#define MHWORDS   (NUM_MACH * NBM)  // 131072 = 128*1024
#define NBLK_M    128               // machine blockhist scan blocks
#define NBLK_T    (NBLK + NBLK_M)   // 324 unified scan blocks

typedef short short8 __attribute__((ext_vector_type(8)));
typedef unsigned short ushort8 __attribute__((ext_vector_type(8)));
typedef float floatx4 __attribute__((ext_vector_type(4)));

__device__ __forceinline__ unsigned short f2bf(float f) {
    unsigned u = __float_as_uint(f);
    unsigned r = (u + 0x7FFFu + ((u >> 16) & 1u)) >> 16;   // RNE
    return (unsigned short)r;
}
__device__ __forceinline__ float bf2f(unsigned short u) {
    return __uint_as_float(((unsigned)u) << 16);
}

// ---------------- prep: op embed (bf16) | mach embed (+bf16) | weights | mach_sum zero --------
__global__ void k_prep(const float* __restrict__ Fo, const float* __restrict__ Fm,
                       const float* __restrict__ Wo, const float* __restrict__ bo,
                       const float* __restrict__ Wm, const float* __restrict__ bm,
                       const float* __restrict__ Wp, const float* __restrict__ Wc,
                       unsigned short* __restrict__ op_ebf,
                       float* __restrict__ mach_emb, unsigned short* __restrict__ mach_ebf,
                       unsigned short* __restrict__ Wb, float* __restrict__ mach_sum) {
    int idx = blockIdx.x * blockDim.x + threadIdx.x;
    if (idx < NUM_OPS * HDIM) {
        int r = idx >> 7, h = idx & 127;
        const float* f = Fo + (size_t)r * 6;
        const float* w = Wo + (size_t)h * 6;
        float s = bo[h];
#pragma unroll
        for (int i = 0; i < 6; ++i) s += f[i] * w[i];
        op_ebf[idx] = f2bf(s);
        return;
    }
    idx -= NUM_OPS * HDIM;
    if (idx < NUM_MACH * HDIM) {
        int r = idx >> 7, h = idx & 127;
        const float* f = Fm + (size_t)r * 2;
        const float* w = Wm + (size_t)h * 2;
        float s = bm[h] + f[0] * w[0] + f[1] * w[1];
        mach_emb[idx] = s;
        mach_ebf[idx] = f2bf(s);
        return;
    }
    idx -= NUM_MACH * HDIM;
    if (idx < 2 * 128 * 256) {
        int l = idx >> 15, h = (idx >> 8) & 127, k = idx & 255;
        float v = (k < 128) ? Wp[(size_t)l * 16384 + h * 128 + k]
                            : Wc[(size_t)l * 16384 + h * 128 + (k - 128)];
        Wb[idx] = f2bf(v);
        return;
    }
    idx -= 2 * 128 * 256;
    if (idx < NUM_MACH * HDIM) mach_sum[idx] = 0.f;
}

// ---------------- front: coarse op-key histogram + machine histogram (shared comp_e read) ----
__global__ __launch_bounds__(256) void k_front(const int* __restrict__ prec_e, int nprec,
                                               const int* __restrict__ comp_e, int E, int M,
                                               int* __restrict__ chist_bh,   // [784][256]
                                               int* __restrict__ mach_bh) {  // [512][256]
    __shared__ int hc[NCOARSE];
    __shared__ int hm[NUM_MACH];
    for (int i = threadIdx.x; i < NCOARSE; i += 256) hc[i] = 0;
    for (int i = threadIdx.x; i < NUM_MACH; i += 256) hm[i] = 0;
    __syncthreads();
    int NT = nprec + E;
    int ch = (NT + NBC - 1) / NBC;
    int i0 = blockIdx.x * ch, i1 = min(NT, i0 + ch);
    for (int i = i0 + threadIdx.x; i < i1; i += 256) {
        int key;
        if (i < nprec) key = prec_e[nprec + i];
        else {
            int e = i - nprec;
            key = P1 + comp_e[e];
            atomicAdd(&hm[comp_e[E + e] - M], 1);
        }
        atomicAdd(&hc[key >> 8], 1);
    }
    __syncthreads();
    for (int i = threadIdx.x; i < NCOARSE; i += 256)
        chist_bh[i * NBC + blockIdx.x] = hc[i];
    for (int i = threadIdx.x; i < NUM_MACH; i += 256)
        mach_bh[i * NBC + blockIdx.x] = hm[i];
}

// ---------------- coarse pass B: place packed (val<<8 | key&255) via LDS cursors ----------------
__global__ __launch_bounds__(256) void k_cfill(const int* __restrict__ prec_e, int nprec,
                                               const int* __restrict__ comp_e, int E, int M,
                                               const int* __restrict__ scan,
                                               int* __restrict__ pairs) {
    __shared__ int cur[NCOARSE];
    for (int i = threadIdx.x; i < NCOARSE; i += 256) cur[i] = scan[i * NBC + blockIdx.x];
    __syncthreads();
    int NT = nprec + E;
    int ch = (NT + NBC - 1) / NBC;
    int i0 = blockIdx.x * ch, i1 = min(NT, i0 + ch);
    for (int i = i0 + threadIdx.x; i < i1; i += 256) {
        int key, val;
        if (i < nprec) { key = prec_e[nprec + i]; val = prec_e[i]; }
        else { int e = i - nprec; key = P1 + comp_e[e]; val = comp_e[E + e] - M; }
        int pos = atomicAdd(&cur[key >> 8], 1);
        pairs[pos] = (val << 8) | (key & 255);
    }
}

// ---------------- scan phase 1: per-block sums over unified [chist|mach_bh] ----------------
__global__ __launch_bounds__(256) void k_blocksum(const int* __restrict__ arr, int* __restrict__ partial) {
    __shared__ int sh[256];
    int b = blockIdx.x, t = threadIdx.x;
    int4 v = *(const int4*)(arr + b * 1024 + t * 4);
    sh[t] = v.x + v.y + v.z + v.w;
    __syncthreads();
    for (int o = 128; o; o >>= 1) { if (t < o) sh[t] += sh[t + o]; __syncthreads(); }
    if (!t) partial[b] = sh[0];
}

// ---------------- scan phase 2: two independent segments (op: 196, machine: 128) --------------
__global__ __launch_bounds__(256) void k_scanpart(const int* __restrict__ partial,
                                                  int* __restrict__ block_off) {
    __shared__ int sh[256];
    int t = threadIdx.x;
    int seg0 = blockIdx.x ? NBLK : 0;
    int n    = blockIdx.x ? NBLK_M : NBLK;
    int v = (t < n) ? partial[seg0 + t] : 0;
    sh[t] = v; __syncthreads();
    for (int o = 1; o < 256; o <<= 1) {
        int x = (t >= o) ? sh[t - o] : 0; __syncthreads();
        sh[t] += x; __syncthreads();
    }
    if (t < n) block_off[seg0 + t] = sh[t] - v;
}

// ---------------- scan phase 3: write exclusive offsets (unified) ----------------
__global__ __launch_bounds__(256) void k_scanwrite(const int* __restrict__ arr,
                                                   const int* __restrict__ block_off,
                                                   int* __restrict__ rs) {
    __shared__ int sh[256];
    int b = blockIdx.x, t = threadIdx.x;
    int base_i = b * 1024 + t * 4;
    int4 v = *(const int4*)(arr + base_i);
    int tsum = v.x + v.y + v.z + v.w;
    sh[t] = tsum; __syncthreads();
    for (int o = 1; o < 256; o <<= 1) {
        int x = (t >= o) ? sh[t - o] : 0; __syncthreads();
        sh[t] += x; __syncthreads();
    }
    int off = block_off[b] + sh[t] - tsum;
    int4 r; r.x = off; r.y = off + v.x; r.z = off + v.x + v.y; r.w = off + v.x + v.y + v.z;
    *(int4*)(rs + base_i) = r;
}

// ---------------- fine counting sort (op keys) + machine placement + mach_rs, one launch -----
__global__ __launch_bounds__(256) void k_finefill(const int* __restrict__ scans, int NT,
                                                  const int* __restrict__ pairs,
                                                  int* __restrict__ rs,
                                                  int* __restrict__ bucket_all,
                                                  const int* __restrict__ comp_e, int E, int M,
                                                  int* __restrict__ bucket_mach,
                                                  int* __restrict__ mach_rs) {
    int t = threadIdx.x;
    if (blockIdx.x < NCOARSE) {
        __shared__ int hh[256];
        __shared__ int ex[256];
        __shared__ int cu[256];
        int b = blockIdx.x;
        int s = scans[b * NBC];
        int e = (b == NCOARSE - 1) ? NT : scans[(b + 1) * NBC];
        hh[t] = 0;
        __syncthreads();
        for (int i = s + t; i < e; i += 256) atomicAdd(&hh[pairs[i] & 255], 1);
        __syncthreads();
        int v = hh[t];
        ex[t] = v; __syncthreads();
        for (int o = 1; o < 256; o <<= 1) {
            int x = (t >= o) ? ex[t - o] : 0; __syncthreads();
            ex[t] += x; __syncthreads();
        }
        int start = s + ex[t] - v;
        rs[b * 256 + t] = start;
        cu[t] = start;
        __syncthreads();
        for (int i = s + t; i < e; i += 256) {
            int p = pairs[i];
            int pos = atomicAdd(&cu[p & 255], 1);
            bucket_all[pos] = ((unsigned)p) >> 8;
        }
    } else {
        __shared__ int cur[NUM_MACH];
        int blk = blockIdx.x - NCOARSE;
        const int* moff = scans + NHIST;
        for (int i = t; i < NUM_MACH; i += 256) cur[i] = moff[i * NBM + blk];
        if (blk == 0) {
            for (int m = t; m < NUM_MACH; m += 256) mach_rs[m] = moff[m * NBM];
            if (t == 0) mach_rs[NUM_MACH] = E;
        }
        __syncthreads();
        int nprec = NT - E;
        int chNT = (NT + NBC - 1) / NBC;            // SAME chunking as k_front
        int e0 = blk * chNT - nprec;       if (e0 < 0) e0 = 0;
        int e1 = (blk + 1) * chNT - nprec; if (e1 > E) e1 = E;
        for (int e = e0 + t; e < e1; e += 256) {
            int m = comp_e[E + e] - M;
            int op = comp_e[e];
            int pos = atomicAdd(&cur[m], 1);
            bucket_mach[pos] = op;
        }
    }
}

#define ACC8(acc, v) { _Pragma("unroll") for (int k = 0; k < 8; ++k) acc[k] += bf2f((unsigned short)v[k]); }

// ---------------- merged per-layer aggregation: op-side gather->Ab | machine-side gather ------
// (r13-verified configuration: op-agg blocks first, NM*4 machine blocks at the grid tail,
//  16-edge staged machine path, stride 1024)
__global__ __launch_bounds__(256) void k_aggmg(
    const unsigned short* __restrict__ op_ebf, const unsigned short* __restrict__ mach_ebf,
    const int* __restrict__ rs, const int* __restrict__ bucket_all,
    unsigned short* __restrict__ Ab, int* __restrict__ flags, int M,
    const int* __restrict__ mach_rs, const int* __restrict__ bucket_mach,
    float* __restrict__ mach_sum, int nb_agg) {
    int wave = threadIdx.x >> 6, lane = threadIdx.x & 63;
    int g = lane >> 4;               // edge sub-group 0..3
    int d = (lane & 15) * 8;         // dim base: 8 bf16 per lane

    if ((int)blockIdx.x < nb_agg) {
        // ---- op aggregation: dual-stream interleaved gather (4 loads in flight) ----
        int r = blockIdx.x * 4 + wave;
        if (r >= M) return;
        int sA = rs[r],      eA = rs[r + 1];
        int sB = rs[P1 + r], eB = rs[P1 + r + 1];

        float a[8], b[8];
#pragma unroll
        for (int k = 0; k < 8; ++k) { a[k] = 0.f; b[k] = 0.f; }

        int baseA = sA, baseB = sB;
        while (baseA < eA || baseB < eB) {
            int cA = (baseA < eA) ? min(64, eA - baseA) : 0;
            int cB = (baseB < eB) ? min(64, eB - baseB) : 0;
            int idxA = (lane < cA) ? bucket_all[baseA + lane] : 0;
            int idxB = (lane < cB) ? bucket_all[baseB + lane] : 0;
            int jm = max(cA, cB);
            for (int j = 0; j < jm; j += 8) {
                int j0 = j + g, j1 = j + 4 + g;
                int rA0 = __shfl(idxA, j0);
                int rA1 = __shfl(idxA, j1);
                int rB0 = __shfl(idxB, j0);
                int rB1 = __shfl(idxB, j1);
                short8 vA0 = *(const short8*)(op_ebf   + (size_t)rA0 * HDIM + d);
                short8 vA1 = *(const short8*)(op_ebf   + (size_t)rA1 * HDIM + d);
                short8 vB0 = *(const short8*)(mach_ebf + (size_t)rB0 * HDIM + d);
                short8 vB1 = *(const short8*)(mach_ebf + (size_t)rB1 * HDIM + d);
                if (j0 < cA) ACC8(a, vA0);
                if (j1 < cA) ACC8(a, vA1);
                if (j0 < cB) ACC8(b, vB0);
                if (j1 < cB) ACC8(b, vB1);
            }
            baseA += 64; baseB += 64;
        }
#pragma unroll
        for (int k = 0; k < 8; ++k) {
            a[k] += __shfl_xor(a[k], 16);
            a[k] += __shfl_xor(a[k], 32);
            b[k] += __shfl_xor(b[k], 16);
            b[k] += __shfl_xor(b[k], 32);
        }
        float pinv = 1.f / fmaxf((float)(eA - sA), 1.f);
        float cinv = 1.f / fmaxf((float)(eB - sB), 1.f);

        if (lane < 16) {
            ushort8 pa, pb;
#pragma unroll
            for (int k = 0; k < 8; ++k) { pa[k] = f2bf(a[k] * pinv); pb[k] = f2bf(b[k] * cinv); }
            *(ushort8*)(Ab + (size_t)r * 256 + d)       = pa;
            *(ushort8*)(Ab + (size_t)r * 256 + 128 + d) = pb;
        }
        if (lane == 0) flags[r] = (eA > sA ? 1 : 0) | (eB > sB ? 2 : 0);
        return;
    }

    // ---- machine gather: 16-edge staged batches, 16 groups/machine, stride 1024 ----
    int b2 = blockIdx.x - nb_agg;
    int m  = b2 & 511;
    int yq = b2 >> 9;                 // 0..3
    int s0 = mach_rs[m], e0 = mach_rs[m + 1];
    float a[8];
#pragma unroll
    for (int k = 0; k < 8; ++k) a[k] = 0.f;

    for (int base = s0 + (yq * 4 + wave) * 64; base < e0; base += 1024) {
        int cnt = min(64, e0 - base);
        int idx = (lane < cnt) ? bucket_mach[base + lane] : 0;
        int j = 0;
        for (; j + 16 <= cnt; j += 16) {
            int r0 = __shfl(idx, j + g);
            int r1 = __shfl(idx, j + 4 + g);
            int r2 = __shfl(idx, j + 8 + g);
            int r3 = __shfl(idx, j + 12 + g);
            short8 v0 = *(const short8*)(op_ebf + (size_t)r0 * HDIM + d);
            short8 v1 = *(const short8*)(op_ebf + (size_t)r1 * HDIM + d);
            short8 v2 = *(const short8*)(op_ebf + (size_t)r2 * HDIM + d);
            short8 v3 = *(const short8*)(op_ebf + (size_t)r3 * HDIM + d);
            ACC8(a, v0); ACC8(a, v1); ACC8(a, v2); ACC8(a, v3);
        }
        for (; j < cnt; j += 4) {
            int jj = j + g;
            int rowi = __shfl(idx, jj);
            short8 v = *(const short8*)(op_ebf + (size_t)rowi * HDIM + d);
            if (jj < cnt) ACC8(a, v);
        }
    }
#pragma unroll
    for (int k = 0; k < 8; ++k) {
        a[k] += __shfl_xor(a[k], 16);
        a[k] += __shfl_xor(a[k], 32);
    }
    if (lane < 16) {
#pragma unroll
        for (int k = 0; k < 8; ++k)
            atomicAdd(&mach_sum[m * HDIM + d + k], a[k]);
    }
}

// ---------------- MFMA GEMM + bf16 residual + LN  |  machine update (tail blocks) ------------
// blocks [0, nb_gemm): op update. blocks [nb_gemm, +NUM_MACH): machine update + mach_sum zero.
__global__ __launch_bounds__(256) void k_gemm_mupd(
    const unsigned short* __restrict__ Ab, const unsigned short* __restrict__ embb,
    const unsigned short* __restrict__ Wb,
    const float* __restrict__ bp, const float* __restrict__ bc,
    const int* __restrict__ flags,
    const float* __restrict__ g, const float* __restrict__ bt,
    float* __restrict__ dstf, unsigned short* __restrict__ dstb, int M, int nb_gemm,
    const float* __restrict__ mach_emb, float* __restrict__ mach_sum,
    const int* __restrict__ mach_rs,
    const float* __restrict__ Wc,
    const float* __restrict__ gm, const float* __restrict__ btm,
    float* __restrict__ mdst, unsigned short* __restrict__ mdstb) {
    if ((int)blockIdx.x >= nb_gemm) {
        // ---- machine update: mean -> @Wc^T + bc -> +emb -> LN; zero mach_sum after read ----
        __shared__ float row[HDIM];
        __shared__ float red[4];
        int m = blockIdx.x - nb_gemm, t = threadIdx.x;
        int cnt = mach_rs[m + 1] - mach_rs[m];
        float sc = (cnt > 0) ? 1.f / (float)cnt : 0.f;
        if (t < HDIM) {
            row[t] = mach_sum[m * HDIM + t] * sc;
            mach_sum[m * HDIM + t] = 0.f;      // ready for next layer's atomics
        }
        __syncthreads();
        float x = 0.f, s = 0.f, q = 0.f;
        if (t < HDIM) {
            float dot = bc[t];
            const float* w = Wc + (size_t)t * HDIM;
#pragma unroll 8
            for (int k = 0; k < HDIM; ++k) dot += row[k] * w[k];
            x = mach_emb[m * HDIM + t] + ((cnt > 0) ? dot : 0.f);
            s = x; q = x * x;
#pragma unroll
            for (int o = 32; o; o >>= 1) { s += __shfl_xor(s, o); q += __shfl_xor(q, o); }
            int wv = t >> 6;
            if ((t & 63) == 0) { red[wv * 2] = s; red[wv * 2 + 1] = q; }
        }
        __syncthreads();
        if (t < HDIM) {
            s = red[0] + red[2]; q = red[1] + red[3];
            float mu = s * (1.f / 128.f);
            float rstd = rsqrtf(fmaxf(q * (1.f / 128.f) - mu * mu, 0.f) + 1e-5f);
            float y = (x - mu) * rstd * gm[t] + btm[t];
            mdst[m * HDIM + t] = y;
            if (mdstb) mdstb[m * HDIM + t] = f2bf(y);
        }
        return;
    }

    int wave = threadIdx.x >> 6, lane = threadIdx.x & 63;
    int m0 = blockIdx.x * 64 + wave * 16;
    if (m0 >= M) return;
    int quad = lane >> 4, col = lane & 15;

    floatx4 acc[8];
#pragma unroll
    for (int t = 0; t < 8; ++t) acc[t] = (floatx4){0.f, 0.f, 0.f, 0.f};

    const short* Arow  = (const short*)(Ab + (size_t)(m0 + col) * 256);
    const short* Wbase = (const short*)Wb;

#pragma unroll
    for (int ks = 0; ks < 8; ++ks) {
        short8 a = *(const short8*)(Arow + ks * 32 + quad * 8);
#pragma unroll
        for (int t = 0; t < 8; ++t) {
            short8 b = *(const short8*)(Wbase + (size_t)(t * 16 + col) * 256 + ks * 32 + quad * 8);
            acc[t] = __builtin_amdgcn_mfma_f32_16x16x32_bf16(a, b, acc[t], 0, 0, 0);
        }
    }

    float bpv[8], bcv[8], gv[8], btv[8];
#pragma unroll
    for (int t = 0; t < 8; ++t) {
        int c = t * 16 + col;
        bpv[t] = bp[c]; bcv[t] = bc[c]; gv[t] = g[c]; btv[t] = bt[c];
    }
#pragma unroll
    for (int reg = 0; reg < 4; ++reg) {
        int r = m0 + quad * 4 + reg;
        int fl = flags[r];
        float fp = (fl & 1) ? 1.f : 0.f, fc = (fl & 2) ? 1.f : 0.f;
        float x[8]; float s = 0.f, q = 0.f;
#pragma unroll
        for (int t = 0; t < 8; ++t) {
            float v = acc[t][reg] + bf2f(embb[(size_t)r * HDIM + t * 16 + col]) + fp * bpv[t] + fc * bcv[t];
            x[t] = v; s += v; q += v * v;
        }
#pragma unroll
        for (int msk = 1; msk < 16; msk <<= 1) { s += __shfl_xor(s, msk); q += __shfl_xor(q, msk); }
        float mu = s * (1.f / 128.f);
        float rstd = rsqrtf(fmaxf(q * (1.f / 128.f) - mu * mu, 0.f) + 1e-5f);
#pragma unroll
        for (int t = 0; t < 8; ++t) {
            float y = (x[t] - mu) * rstd * gv[t] + btv[t];
            if (dstf) dstf[(size_t)r * HDIM + t * 16 + col] = y;
            if (dstb) dstb[(size_t)r * HDIM + t * 16 + col] = f2bf(y);
        }
    }
}

extern "C" void kernel_launch(void* const* d_in, const int* in_sizes, int n_in,
                              void* d_out, int out_size, void* d_ws, size_t ws_size,
                              hipStream_t stream) {
    const float* op_feat    = (const float*)d_in[0];
    const float* m_feat     = (const float*)d_in[1];
    const int*   prec_e     = (const int*)d_in[2];
    const int*   comp_e     = (const int*)d_in[3];
    const float* op_emb_W   = (const float*)d_in[4];
    const float* op_emb_b   = (const float*)d_in[5];
    const float* mach_emb_W = (const float*)d_in[6];
    const float* mach_emb_b = (const float*)d_in[7];
    const float* prec_W     = (const float*)d_in[8];
    const float* prec_b     = (const float*)d_in[9];
    const float* compat_W   = (const float*)d_in[10];
    const float* compat_b   = (const float*)d_in[11];
    const float* op_ln_g    = (const float*)d_in[12];
    const float* op_ln_b    = (const float*)d_in[13];
    const float* mach_ln_g  = (const float*)d_in[14];
    const float* mach_ln_b  = (const float*)d_in[15];
    float* out = (float*)d_out;

    const int M = NUM_OPS, NM = NUM_MACH;
    const int nprec = in_sizes[2] / 2;
    const int ncomp = in_sizes[3] / 2;
    const int E = ncomp / 2;   // bidirectional pairs: first half o2m, second half m2o (mirror)
    const int NT = nprec + E;

    float* ws = (float*)d_ws;
    size_t o = 0;
    unsigned short* op_ebf = (unsigned short*)(ws + o); o += (size_t)M * 64;   // 25.6 MB bf16 state
    unsigned short* Ab = (unsigned short*)(ws + o); o += (size_t)M * 128;  // 51 MB bf16 [M][256]
    unsigned short* Wb = (unsigned short*)(ws + o); o += 32768;            // 2 layers x [128][256] bf16
    float* mach_emb = ws + o; o += (size_t)NM * HDIM;
    unsigned short* mach_ebf = (unsigned short*)(ws + o); o += (size_t)NM * 64;
    float* mach_sum = ws + o; o += (size_t)NM * HDIM;
    int* ip = (int*)(ws + o);
    size_t io = 0;
    int* hists     = ip + io; io += NHIST + MHWORDS;  // [chist 784x256 | mach_bh 512x256]
    int* scans     = ip + io; io += NHIST + MHWORDS;  // [cscan | moff] (exclusive offsets)
    int* rs        = ip + io; io += NHIST;            // fine row starts (exclusive)
    int* mach_rs   = ip + io; io += NM + 8;
    int* partialT  = ip + io; io += 512;              // unified block sums (324 used)
    int* block_off = ip + io; io += 512;
    int* flags     = ip + io; io += M;
    int* pairs     = ip + io; io += (size_t)NT;       // coarse-partitioned packed edges
    int* bucket_all  = ip + io; io += (size_t)NT;
    int* bucket_mach = ip + io; io += (size_t)E;

    int* mach_bh = hists + NHIST;

    // ---- CSR build: two-level counting sort, 6 launches ----
    k_front<<<NBC, 256, 0, stream>>>(prec_e, nprec, comp_e, E, M, hists, mach_bh);
    k_blocksum<<<NBLK_T, 256, 0, stream>>>(hists, partialT);
    k_scanpart<<<2, 256, 0, stream>>>(partialT, block_off);
    k_scanwrite<<<NBLK_T, 256, 0, stream>>>(hists, block_off, scans);
    k_cfill<<<NBC, 256, 0, stream>>>(prec_e, nprec, comp_e, E, M, scans, pairs);
    k_finefill<<<NCOARSE + NBM, 256, 0, stream>>>(scans, NT, pairs, rs, bucket_all,
                                                  comp_e, E, M, bucket_mach, mach_rs);

    // ---- embeddings + weight conversion + mach_sum zero, one launch ----
    int prep_total = (M + 2 * NM) * HDIM + 2 * 128 * 256;
    k_prep<<<(prep_total + 255) / 256, 256, 0, stream>>>(
        op_feat, m_feat, op_emb_W, op_emb_b, mach_emb_W, mach_emb_b,
        prec_W, compat_W, op_ebf, mach_emb, mach_ebf, Wb, mach_sum);

    const int nb_agg = (M + 3) / 4;      // 1 row per wave, 4 waves per block (r9 config)
    const int nb_gemm = (M + 63) / 64;
    for (int l = 0; l < 2; ++l) {
        int last = (l == 1);
        const float* bpl = prec_b   + (size_t)l * HDIM;
        const float* Wc  = compat_W + (size_t)l * HDIM * HDIM;
        const float* bcl = compat_b + (size_t)l * HDIM;

        // merged: op-side aggregation (writes Ab/flags) + machine-side gather (atomics mach_sum)
        k_aggmg<<<nb_agg + NM * 4, 256, 0, stream>>>(
            op_ebf, mach_ebf, rs, bucket_all, Ab, flags, M,
            mach_rs, bucket_mach, mach_sum, nb_agg);

        // merged: op update (MFMA+LN, in-place bf16 state) + machine update (zeroes mach_sum)
        k_gemm_mupd<<<nb_gemm + NM, 256, 0, stream>>>(
            Ab, op_ebf, Wb + (size_t)l * 128 * 256, bpl, bcl, flags,
            op_ln_g + (size_t)l * HDIM, op_ln_b + (size_t)l * HDIM,
            last ? out : nullptr, last ? nullptr : op_ebf, M, nb_gemm,
            mach_emb, mach_sum, mach_rs, Wc,
            mach_ln_g + (size_t)l * HDIM, mach_ln_b + (size_t)l * HDIM,
            last ? (out + (size_t)M * HDIM) : mach_emb, last ? nullptr : mach_ebf);
    }
}

// Round 17
// 513.123 us; speedup vs baseline: 1.1275x; 1.0159x over previous
//
#include <hip/hip_runtime.h>
#include <hip/hip_bf16.h>

#define NUM_OPS   100000
#define NUM_MACH  512
#define HDIM      128
#define P1        100352            // m2o key offset (98*1024)
#define NHIST     200704            // 196*1024 == 784*256 combined key space
#define NBLK      196               // op-hist scan blocks (1024 elems each)
#define NCOARSE   784               // coarse buckets (key >> 8)
#define NBC       256               // blocks for coarse hist/fill passes
#define NBM       256               // counting-sort blocks for machine buckets
#define MHWORDS   (NUM_MACH * NBM)  // 131072 = 128*1024
#define NBLK_M    128               // machine blockhist scan blocks
#define NBLK_T    (NBLK + NBLK_M)   // 324 unified scan blocks
#define NB_PREP   1024              // prep blocks appended to k_front's grid

typedef short short8 __attribute__((ext_vector_type(8)));
typedef unsigned short ushort8 __attribute__((ext_vector_type(8)));
typedef float floatx4 __attribute__((ext_vector_type(4)));

__device__ __forceinline__ unsigned short f2bf(float f) {
    unsigned u = __float_as_uint(f);
    unsigned r = (u + 0x7FFFu + ((u >> 16) & 1u)) >> 16;   // RNE
    return (unsigned short)r;
}
__device__ __forceinline__ float bf2f(unsigned short u) {
    return __uint_as_float(((unsigned)u) << 16);
}

// ---------------- front+prep: histograms (blocks 0-255) | embeds/weights/zero (256+) ----------
// The two halves are fully independent (edges vs features); concatenated into one grid to
// remove a dispatch boundary and overlap prep under the histogram pass.
__global__ __launch_bounds__(256) void k_front(const int* __restrict__ prec_e, int nprec,
                                               const int* __restrict__ comp_e, int E, int M,
                                               int* __restrict__ chist_bh,   // [784][256]
                                               int* __restrict__ mach_bh,    // [512][256]
                                               const float* __restrict__ Fo, const float* __restrict__ Fm,
                                               const float* __restrict__ Wo, const float* __restrict__ bo,
                                               const float* __restrict__ Wm, const float* __restrict__ bm,
                                               const float* __restrict__ Wp, const float* __restrict__ Wc,
                                               unsigned short* __restrict__ op_ebf,
                                               float* __restrict__ mach_emb,
                                               unsigned short* __restrict__ mach_ebf,
                                               unsigned short* __restrict__ Wb,
                                               float* __restrict__ mach_sum) {
    int t = threadIdx.x;
    if (blockIdx.x >= NBC) {
        // ---- prep path: op embed bf16 | mach embed f32+bf16 | weight conv | mach_sum zero ----
        const int T0 = NUM_OPS * HDIM;
        const int T1 = T0 + NUM_MACH * HDIM;
        const int T2 = T1 + 2 * 128 * 256;
        const int T3 = T2 + NUM_MACH * HDIM;
        int stride = NB_PREP * 256;
        for (int idx = (blockIdx.x - NBC) * 256 + t; idx < T3; idx += stride) {
            if (idx < T0) {
                int r = idx >> 7, h = idx & 127;
                const float* f = Fo + (size_t)r * 6;
                const float* w = Wo + (size_t)h * 6;
                float s = bo[h];
#pragma unroll
                for (int i = 0; i < 6; ++i) s += f[i] * w[i];
                op_ebf[idx] = f2bf(s);
            } else if (idx < T1) {
                int j = idx - T0;
                int r = j >> 7, h = j & 127;
                const float* f = Fm + (size_t)r * 2;
                const float* w = Wm + (size_t)h * 2;
                float s = bm[h] + f[0] * w[0] + f[1] * w[1];
                mach_emb[j] = s;
                mach_ebf[j] = f2bf(s);
            } else if (idx < T2) {
                int j = idx - T1;
                int l = j >> 15, h = (j >> 8) & 127, k = j & 255;
                float v = (k < 128) ? Wp[(size_t)l * 16384 + h * 128 + k]
                                    : Wc[(size_t)l * 16384 + h * 128 + (k - 128)];
                Wb[j] = f2bf(v);
            } else {
                mach_sum[idx - T2] = 0.f;
            }
        }
        return;
    }

    __shared__ int hc[NCOARSE];
    __shared__ int hm[NUM_MACH];
    for (int i = t; i < NCOARSE; i += 256) hc[i] = 0;
    for (int i = t; i < NUM_MACH; i += 256) hm[i] = 0;
    __syncthreads();
    int NT = nprec + E;
    int ch = (NT + NBC - 1) / NBC;
    int i0 = blockIdx.x * ch, i1 = min(NT, i0 + ch);
    for (int i = i0 + t; i < i1; i += 256) {
        int key;
        if (i < nprec) key = prec_e[nprec + i];
        else {
            int e = i - nprec;
            key = P1 + comp_e[e];
            atomicAdd(&hm[comp_e[E + e] - M], 1);
        }
        atomicAdd(&hc[key >> 8], 1);
    }
    __syncthreads();
    for (int i = t; i < NCOARSE; i += 256)
        chist_bh[i * NBC + blockIdx.x] = hc[i];
    for (int i = t; i < NUM_MACH; i += 256)
        mach_bh[i * NBC + blockIdx.x] = hm[i];
}

// ---------------- coarse pass B: place packed (val<<8 | key&255) via LDS cursors ----------------
__global__ __launch_bounds__(256) void k_cfill(const int* __restrict__ prec_e, int nprec,
                                               const int* __restrict__ comp_e, int E, int M,
                                               const int* __restrict__ scan,
                                               int* __restrict__ pairs) {
    __shared__ int cur[NCOARSE];
    for (int i = threadIdx.x; i < NCOARSE; i += 256) cur[i] = scan[i * NBC + blockIdx.x];
    __syncthreads();
    int NT = nprec + E;
    int ch = (NT + NBC - 1) / NBC;
    int i0 = blockIdx.x * ch, i1 = min(NT, i0 + ch);
    for (int i = i0 + threadIdx.x; i < i1; i += 256) {
        int key, val;
        if (i < nprec) { key = prec_e[nprec + i]; val = prec_e[i]; }
        else { int e = i - nprec; key = P1 + comp_e[e]; val = comp_e[E + e] - M; }
        int pos = atomicAdd(&cur[key >> 8], 1);
        pairs[pos] = (val << 8) | (key & 255);
    }
}

// ---------------- scan phase 1: per-block sums over unified [chist|mach_bh] ----------------
__global__ __launch_bounds__(256) void k_blocksum(const int* __restrict__ arr, int* __restrict__ partial) {
    __shared__ int sh[256];
    int b = blockIdx.x, t = threadIdx.x;
    int4 v = *(const int4*)(arr + b * 1024 + t * 4);
    sh[t] = v.x + v.y + v.z + v.w;
    __syncthreads();
    for (int o = 128; o; o >>= 1) { if (t < o) sh[t] += sh[t + o]; __syncthreads(); }
    if (!t) partial[b] = sh[0];
}

// ---------------- scan phase 2: two independent segments (op: 196, machine: 128) --------------
__global__ __launch_bounds__(256) void k_scanpart(const int* __restrict__ partial,
                                                  int* __restrict__ block_off) {
    __shared__ int sh[256];
    int t = threadIdx.x;
    int seg0 = blockIdx.x ? NBLK : 0;
    int n    = blockIdx.x ? NBLK_M : NBLK;
    int v = (t < n) ? partial[seg0 + t] : 0;
    sh[t] = v; __syncthreads();
    for (int o = 1; o < 256; o <<= 1) {
        int x = (t >= o) ? sh[t - o] : 0; __syncthreads();
        sh[t] += x; __syncthreads();
    }
    if (t < n) block_off[seg0 + t] = sh[t] - v;
}

// ---------------- scan phase 3: write exclusive offsets (unified) ----------------
__global__ __launch_bounds__(256) void k_scanwrite(const int* __restrict__ arr,
                                                   const int* __restrict__ block_off,
                                                   int* __restrict__ rs) {
    __shared__ int sh[256];
    int b = blockIdx.x, t = threadIdx.x;
    int base_i = b * 1024 + t * 4;
    int4 v = *(const int4*)(arr + base_i);
    int tsum = v.x + v.y + v.z + v.w;
    sh[t] = tsum; __syncthreads();
    for (int o = 1; o < 256; o <<= 1) {
        int x = (t >= o) ? sh[t - o] : 0; __syncthreads();
        sh[t] += x; __syncthreads();
    }
    int off = block_off[b] + sh[t] - tsum;
    int4 r; r.x = off; r.y = off + v.x; r.z = off + v.x + v.y; r.w = off + v.x + v.y + v.z;
    *(int4*)(rs + base_i) = r;
}

// ---------------- fine counting sort (op keys) + machine placement + mach_rs, one launch -----
__global__ __launch_bounds__(256) void k_finefill(const int* __restrict__ scans, int NT,
                                                  const int* __restrict__ pairs,
                                                  int* __restrict__ rs,
                                                  int* __restrict__ bucket_all,
                                                  const int* __restrict__ comp_e, int E, int M,
                                                  int* __restrict__ bucket_mach,
                                                  int* __restrict__ mach_rs) {
    int t = threadIdx.x;
    if (blockIdx.x < NCOARSE) {
        __shared__ int hh[256];
        __shared__ int ex[256];
        __shared__ int cu[256];
        int b = blockIdx.x;
        int s = scans[b * NBC];
        int e = (b == NCOARSE - 1) ? NT : scans[(b + 1) * NBC];
        hh[t] = 0;
        __syncthreads();
        for (int i = s + t; i < e; i += 256) atomicAdd(&hh[pairs[i] & 255], 1);
        __syncthreads();
        int v = hh[t];
        ex[t] = v; __syncthreads();
        for (int o = 1; o < 256; o <<= 1) {
            int x = (t >= o) ? ex[t - o] : 0; __syncthreads();
            ex[t] += x; __syncthreads();
        }
        int start = s + ex[t] - v;
        rs[b * 256 + t] = start;
        cu[t] = start;
        __syncthreads();
        for (int i = s + t; i < e; i += 256) {
            int p = pairs[i];
            int pos = atomicAdd(&cu[p & 255], 1);
            bucket_all[pos] = ((unsigned)p) >> 8;
        }
    } else {
        __shared__ int cur[NUM_MACH];
        int blk = blockIdx.x - NCOARSE;
        const int* moff = scans + NHIST;
        for (int i = t; i < NUM_MACH; i += 256) cur[i] = moff[i * NBM + blk];
        if (blk == 0) {
            for (int m = t; m < NUM_MACH; m += 256) mach_rs[m] = moff[m * NBM];
            if (t == 0) mach_rs[NUM_MACH] = E;
        }
        __syncthreads();
        int nprec = NT - E;
        int chNT = (NT + NBC - 1) / NBC;            // SAME chunking as k_front
        int e0 = blk * chNT - nprec;       if (e0 < 0) e0 = 0;
        int e1 = (blk + 1) * chNT - nprec; if (e1 > E) e1 = E;
        for (int e = e0 + t; e < e1; e += 256) {
            int m = comp_e[E + e] - M;
            int op = comp_e[e];
            int pos = atomicAdd(&cur[m], 1);
            bucket_mach[pos] = op;
        }
    }
}

#define ACC8(acc, v) { _Pragma("unroll") for (int k = 0; k < 8; ++k) acc[k] += bf2f((unsigned short)v[k]); }

// ---------------- merged per-layer aggregation: op-side gather->Ab | machine-side gather ------
// (r13-verified configuration: op-agg blocks first, NM*4 machine blocks at the grid tail,
//  16-edge staged machine path, stride 1024)
__global__ __launch_bounds__(256) void k_aggmg(
    const unsigned short* __restrict__ op_ebf, const unsigned short* __restrict__ mach_ebf,
    const int* __restrict__ rs, const int* __restrict__ bucket_all,
    unsigned short* __restrict__ Ab, int* __restrict__ flags, int M,
    const int* __restrict__ mach_rs, const int* __restrict__ bucket_mach,
    float* __restrict__ mach_sum, int nb_agg) {
    int wave = threadIdx.x >> 6, lane = threadIdx.x & 63;
    int g = lane >> 4;               // edge sub-group 0..3
    int d = (lane & 15) * 8;         // dim base: 8 bf16 per lane

    if ((int)blockIdx.x < nb_agg) {
        // ---- op aggregation: dual-stream interleaved gather (4 loads in flight) ----
        int r = blockIdx.x * 4 + wave;
        if (r >= M) return;
        int sA = rs[r],      eA = rs[r + 1];
        int sB = rs[P1 + r], eB = rs[P1 + r + 1];

        float a[8], b[8];
#pragma unroll
        for (int k = 0; k < 8; ++k) { a[k] = 0.f; b[k] = 0.f; }

        int baseA = sA, baseB = sB;
        while (baseA < eA || baseB < eB) {
            int cA = (baseA < eA) ? min(64, eA - baseA) : 0;
            int cB = (baseB < eB) ? min(64, eB - baseB) : 0;
            int idxA = (lane < cA) ? bucket_all[baseA + lane] : 0;
            int idxB = (lane < cB) ? bucket_all[baseB + lane] : 0;
            int jm = max(cA, cB);
            for (int j = 0; j < jm; j += 8) {
                int j0 = j + g, j1 = j + 4 + g;
                int rA0 = __shfl(idxA, j0);
                int rA1 = __shfl(idxA, j1);
                int rB0 = __shfl(idxB, j0);
                int rB1 = __shfl(idxB, j1);
                short8 vA0 = *(const short8*)(op_ebf   + (size_t)rA0 * HDIM + d);
                short8 vA1 = *(const short8*)(op_ebf   + (size_t)rA1 * HDIM + d);
                short8 vB0 = *(const short8*)(mach_ebf + (size_t)rB0 * HDIM + d);
                short8 vB1 = *(const short8*)(mach_ebf + (size_t)rB1 * HDIM + d);
                if (j0 < cA) ACC8(a, vA0);
                if (j1 < cA) ACC8(a, vA1);
                if (j0 < cB) ACC8(b, vB0);
                if (j1 < cB) ACC8(b, vB1);
            }
            baseA += 64; baseB += 64;
        }
#pragma unroll
        for (int k = 0; k < 8; ++k) {
            a[k] += __shfl_xor(a[k], 16);
            a[k] += __shfl_xor(a[k], 32);
            b[k] += __shfl_xor(b[k], 16);
            b[k] += __shfl_xor(b[k], 32);
        }
        float pinv = 1.f / fmaxf((float)(eA - sA), 1.f);
        float cinv = 1.f / fmaxf((float)(eB - sB), 1.f);

        if (lane < 16) {
            ushort8 pa, pb;
#pragma unroll
            for (int k = 0; k < 8; ++k) { pa[k] = f2bf(a[k] * pinv); pb[k] = f2bf(b[k] * cinv); }
            *(ushort8*)(Ab + (size_t)r * 256 + d)       = pa;
            *(ushort8*)(Ab + (size_t)r * 256 + 128 + d) = pb;
        }
        if (lane == 0) flags[r] = (eA > sA ? 1 : 0) | (eB > sB ? 2 : 0);
        return;
    }

    // ---- machine gather: 16-edge staged batches, 16 groups/machine, stride 1024 ----
    int b2 = blockIdx.x - nb_agg;
    int m  = b2 & 511;
    int yq = b2 >> 9;                 // 0..3
    int s0 = mach_rs[m], e0 = mach_rs[m + 1];
    float a[8];
#pragma unroll
    for (int k = 0; k < 8; ++k) a[k] = 0.f;

    for (int base = s0 + (yq * 4 + wave) * 64; base < e0; base += 1024) {
        int cnt = min(64, e0 - base);
        int idx = (lane < cnt) ? bucket_mach[base + lane] : 0;
        int j = 0;
        for (; j + 16 <= cnt; j += 16) {
            int r0 = __shfl(idx, j + g);
            int r1 = __shfl(idx, j + 4 + g);
            int r2 = __shfl(idx, j + 8 + g);
            int r3 = __shfl(idx, j + 12 + g);
            short8 v0 = *(const short8*)(op_ebf + (size_t)r0 * HDIM + d);
            short8 v1 = *(const short8*)(op_ebf + (size_t)r1 * HDIM + d);
            short8 v2 = *(const short8*)(op_ebf + (size_t)r2 * HDIM + d);
            short8 v3 = *(const short8*)(op_ebf + (size_t)r3 * HDIM + d);
            ACC8(a, v0); ACC8(a, v1); ACC8(a, v2); ACC8(a, v3);
        }
        for (; j < cnt; j += 4) {
            int jj = j + g;
            int rowi = __shfl(idx, jj);
            short8 v = *(const short8*)(op_ebf + (size_t)rowi * HDIM + d);
            if (jj < cnt) ACC8(a, v);
        }
    }
#pragma unroll
    for (int k = 0; k < 8; ++k) {
        a[k] += __shfl_xor(a[k], 16);
        a[k] += __shfl_xor(a[k], 32);
    }
    if (lane < 16) {
#pragma unroll
        for (int k = 0; k < 8; ++k)
            atomicAdd(&mach_sum[m * HDIM + d + k], a[k]);
    }
}

// ---------------- MFMA GEMM + bf16 residual + LN  |  machine update (tail blocks) ------------
// blocks [0, nb_gemm): op update. blocks [nb_gemm, +NUM_MACH): machine update + mach_sum zero.
__global__ __launch_bounds__(256) void k_gemm_mupd(
    const unsigned short* __restrict__ Ab, const unsigned short* __restrict__ embb,
    const unsigned short* __restrict__ Wb,
    const float* __restrict__ bp, const float* __restrict__ bc,
    const int* __restrict__ flags,
    const float* __restrict__ g, const float* __restrict__ bt,
    float* __restrict__ dstf, unsigned short* __restrict__ dstb, int M, int nb_gemm,
    const float* __restrict__ mach_emb, float* __restrict__ mach_sum,
    const int* __restrict__ mach_rs,
    const float* __restrict__ Wc,
    const float* __restrict__ gm, const float* __restrict__ btm,
    float* __restrict__ mdst, unsigned short* __restrict__ mdstb) {
    if ((int)blockIdx.x >= nb_gemm) {
        // ---- machine update: mean -> @Wc^T + bc -> +emb -> LN; zero mach_sum after read ----
        __shared__ float row[HDIM];
        __shared__ float red[4];
        int m = blockIdx.x - nb_gemm, t = threadIdx.x;
        int cnt = mach_rs[m + 1] - mach_rs[m];
        float sc = (cnt > 0) ? 1.f / (float)cnt : 0.f;
        if (t < HDIM) {
            row[t] = mach_sum[m * HDIM + t] * sc;
            mach_sum[m * HDIM + t] = 0.f;      // ready for next layer's atomics
        }
        __syncthreads();
        float x = 0.f, s = 0.f, q = 0.f;
        if (t < HDIM) {
            float dot = bc[t];
            const float* w = Wc + (size_t)t * HDIM;
#pragma unroll 8
            for (int k = 0; k < HDIM; ++k) dot += row[k] * w[k];
            x = mach_emb[m * HDIM + t] + ((cnt > 0) ? dot : 0.f);
            s = x; q = x * x;
#pragma unroll
            for (int o = 32; o; o >>= 1) { s += __shfl_xor(s, o); q += __shfl_xor(q, o); }
            int wv = t >> 6;
            if ((t & 63) == 0) { red[wv * 2] = s; red[wv * 2 + 1] = q; }
        }
        __syncthreads();
        if (t < HDIM) {
            s = red[0] + red[2]; q = red[1] + red[3];
            float mu = s * (1.f / 128.f);
            float rstd = rsqrtf(fmaxf(q * (1.f / 128.f) - mu * mu, 0.f) + 1e-5f);
            float y = (x - mu) * rstd * gm[t] + btm[t];
            mdst[m * HDIM + t] = y;
            if (mdstb) mdstb[m * HDIM + t] = f2bf(y);
        }
        return;
    }

    int wave = threadIdx.x >> 6, lane = threadIdx.x & 63;
    int m0 = blockIdx.x * 64 + wave * 16;
    if (m0 >= M) return;
    int quad = lane >> 4, col = lane & 15;

    floatx4 acc[8];
#pragma unroll
    for (int t = 0; t < 8; ++t) acc[t] = (floatx4){0.f, 0.f, 0.f, 0.f};

    const short* Arow  = (const short*)(Ab + (size_t)(m0 + col) * 256);
    const short* Wbase = (const short*)Wb;

#pragma unroll
    for (int ks = 0; ks < 8; ++ks) {
        short8 a = *(const short8*)(Arow + ks * 32 + quad * 8);
#pragma unroll
        for (int t = 0; t < 8; ++t) {
            short8 b = *(const short8*)(Wbase + (size_t)(t * 16 + col) * 256 + ks * 32 + quad * 8);
            acc[t] = __builtin_amdgcn_mfma_f32_16x16x32_bf16(a, b, acc[t], 0, 0, 0);
        }
    }

    float bpv[8], bcv[8], gv[8], btv[8];
#pragma unroll
    for (int t = 0; t < 8; ++t) {
        int c = t * 16 + col;
        bpv[t] = bp[c]; bcv[t] = bc[c]; gv[t] = g[c]; btv[t] = bt[c];
    }
#pragma unroll
    for (int reg = 0; reg < 4; ++reg) {
        int r = m0 + quad * 4 + reg;
        int fl = flags[r];
        float fp = (fl & 1) ? 1.f : 0.f, fc = (fl & 2) ? 1.f : 0.f;
        float x[8]; float s = 0.f, q = 0.f;
#pragma unroll
        for (int t = 0; t < 8; ++t) {
            float v = acc[t][reg] + bf2f(embb[(size_t)r * HDIM + t * 16 + col]) + fp * bpv[t] + fc * bcv[t];
            x[t] = v; s += v; q += v * v;
        }
#pragma unroll
        for (int msk = 1; msk < 16; msk <<= 1) { s += __shfl_xor(s, msk); q += __shfl_xor(q, msk); }
        float mu = s * (1.f / 128.f);
        float rstd = rsqrtf(fmaxf(q * (1.f / 128.f) - mu * mu, 0.f) + 1e-5f);
#pragma unroll
        for (int t = 0; t < 8; ++t) {
            float y = (x[t] - mu) * rstd * gv[t] + btv[t];
            if (dstf) dstf[(size_t)r * HDIM + t * 16 + col] = y;
            if (dstb) dstb[(size_t)r * HDIM + t * 16 + col] = f2bf(y);
        }
    }
}

extern "C" void kernel_launch(void* const* d_in, const int* in_sizes, int n_in,
                              void* d_out, int out_size, void* d_ws, size_t ws_size,
                              hipStream_t stream) {
    const float* op_feat    = (const float*)d_in[0];
    const float* m_feat     = (const float*)d_in[1];
    const int*   prec_e     = (const int*)d_in[2];
    const int*   comp_e     = (const int*)d_in[3];
    const float* op_emb_W   = (const float*)d_in[4];
    const float* op_emb_b   = (const float*)d_in[5];
    const float* mach_emb_W = (const float*)d_in[6];
    const float* mach_emb_b = (const float*)d_in[7];
    const float* prec_W     = (const float*)d_in[8];
    const float* prec_b     = (const float*)d_in[9];
    const float* compat_W   = (const float*)d_in[10];
    const float* compat_b   = (const float*)d_in[11];
    const float* op_ln_g    = (const float*)d_in[12];
    const float* op_ln_b    = (const float*)d_in[13];
    const float* mach_ln_g  = (const float*)d_in[14];
    const float* mach_ln_b  = (const float*)d_in[15];
    float* out = (float*)d_out;

    const int M = NUM_OPS, NM = NUM_MACH;
    const int nprec = in_sizes[2] / 2;
    const int ncomp = in_sizes[3] / 2;
    const int E = ncomp / 2;   // bidirectional pairs: first half o2m, second half m2o (mirror)
    const int NT = nprec + E;

    float* ws = (float*)d_ws;
    size_t o = 0;
    unsigned short* op_ebf = (unsigned short*)(ws + o); o += (size_t)M * 64;   // 25.6 MB bf16 state
    unsigned short* Ab = (unsigned short*)(ws + o); o += (size_t)M * 128;  // 51 MB bf16 [M][256]
    unsigned short* Wb = (unsigned short*)(ws + o); o += 32768;            // 2 layers x [128][256] bf16
    float* mach_emb = ws + o; o += (size_t)NM * HDIM;
    unsigned short* mach_ebf = (unsigned short*)(ws + o); o += (size_t)NM * 64;
    float* mach_sum = ws + o; o += (size_t)NM * HDIM;
    int* ip = (int*)(ws + o);
    size_t io = 0;
    int* hists     = ip + io; io += NHIST + MHWORDS;  // [chist 784x256 | mach_bh 512x256]
    int* scans     = ip + io; io += NHIST + MHWORDS;  // [cscan | moff] (exclusive offsets)
    int* rs        = ip + io; io += NHIST;            // fine row starts (exclusive)
    int* mach_rs   = ip + io; io += NM + 8;
    int* partialT  = ip + io; io += 512;              // unified block sums (324 used)
    int* block_off = ip + io; io += 512;
    int* flags     = ip + io; io += M;
    int* pairs     = ip + io; io += (size_t)NT;       // coarse-partitioned packed edges
    int* bucket_all  = ip + io; io += (size_t)NT;
    int* bucket_mach = ip + io; io += (size_t)E;

    int* mach_bh = hists + NHIST;

    // ---- CSR build + prep: front/prep merged, then scan chain (6 launches total) ----
    k_front<<<NBC + NB_PREP, 256, 0, stream>>>(prec_e, nprec, comp_e, E, M, hists, mach_bh,
                                               op_feat, m_feat, op_emb_W, op_emb_b,
                                               mach_emb_W, mach_emb_b, prec_W, compat_W,
                                               op_ebf, mach_emb, mach_ebf, Wb, mach_sum);
    k_blocksum<<<NBLK_T, 256, 0, stream>>>(hists, partialT);
    k_scanpart<<<2, 256, 0, stream>>>(partialT, block_off);
    k_scanwrite<<<NBLK_T, 256, 0, stream>>>(hists, block_off, scans);
    k_cfill<<<NBC, 256, 0, stream>>>(prec_e, nprec, comp_e, E, M, scans, pairs);
    k_finefill<<<NCOARSE + NBM, 256, 0, stream>>>(scans, NT, pairs, rs, bucket_all,
                                                  comp_e, E, M, bucket_mach, mach_rs);

    const int nb_agg = (M + 3) / 4;      // 1 row per wave, 4 waves per block (r9 config)
    const int nb_gemm = (M + 63) / 64;
    for (int l = 0; l < 2; ++l) {
        int last = (l == 1);
        const float* bpl = prec_b   + (size_t)l * HDIM;
        const float* Wc  = compat_W + (size_t)l * HDIM * HDIM;
        const float* bcl = compat_b + (size_t)l * HDIM;

        // merged: op-side aggregation (writes Ab/flags) + machine-side gather (atomics mach_sum)
        k_aggmg<<<nb_agg + NM * 4, 256, 0, stream>>>(
            op_ebf, mach_ebf, rs, bucket_all, Ab, flags, M,
            mach_rs, bucket_mach, mach_sum, nb_agg);

        // merged: op update (MFMA+LN, in-place bf16 state) + machine update (zeroes mach_sum)
        k_gemm_mupd<<<nb_gemm + NM, 256, 0, stream>>>(
            Ab, op_ebf, Wb + (size_t)l * 128 * 256, bpl, bcl, flags,
            op_ln_g + (size_t)l * HDIM, op_ln_b + (size_t)l * HDIM,
            last ? out : nullptr, last ? nullptr : op_ebf, M, nb_gemm,
            mach_emb, mach_sum, mach_rs, Wc,
            mach_ln_g + (size_t)l * HDIM, mach_ln_b + (size_t)l * HDIM,
            last ? (out + (size_t)M * HDIM) : mach_emb, last ? nullptr : mach_ebf);
    }
}

// Round 18
// 511.301 us; speedup vs baseline: 1.1315x; 1.0036x over previous
//
#include <hip/hip_runtime.h>
#include <hip/hip_bf16.h>

#define NUM_OPS   100000
#define NUM_MACH  512
#define HDIM      128
#define P1        100352            // m2o key offset (98*1024)
#define NHIST     200704            // 196*1024 == 784*256 combined key space
#define NBLK      196               // op-hist scan blocks (1024 elems each)
#define NCOARSE   784               // coarse buckets (key >> 8)
#define NBC       256               // blocks for coarse hist/fill passes
#define NBM       256               // counting-sort blocks for machine buckets
#define MHWORDS   (NUM_MACH * NBM)  // 131072 = 128*1024
#define NBLK_M    128               // machine blockhist scan blocks
#define NBLK_T    (NBLK + NBLK_M)   // 324 unified scan blocks
#define NB_PREP   1024              // prep blocks appended to k_front's grid

typedef short short8 __attribute__((ext_vector_type(8)));
typedef unsigned short ushort8 __attribute__((ext_vector_type(8)));
typedef float floatx4 __attribute__((ext_vector_type(4)));

__device__ __forceinline__ unsigned short f2bf(float f) {
    unsigned u = __float_as_uint(f);
    unsigned r = (u + 0x7FFFu + ((u >> 16) & 1u)) >> 16;   // RNE
    return (unsigned short)r;
}
__device__ __forceinline__ float bf2f(unsigned short u) {
    return __uint_as_float(((unsigned)u) << 16);
}

// ---------------- front+prep: histograms (blocks 0-255) | embeds/weights/zero (256+) ----------
__global__ __launch_bounds__(256) void k_front(const int* __restrict__ prec_e, int nprec,
                                               const int* __restrict__ comp_e, int E, int M,
                                               int* __restrict__ chist_bh,   // [784][256]
                                               int* __restrict__ mach_bh,    // [512][256]
                                               const float* __restrict__ Fo, const float* __restrict__ Fm,
                                               const float* __restrict__ Wo, const float* __restrict__ bo,
                                               const float* __restrict__ Wm, const float* __restrict__ bm,
                                               const float* __restrict__ Wp, const float* __restrict__ Wc,
                                               unsigned short* __restrict__ op_ebf,
                                               float* __restrict__ mach_emb,
                                               unsigned short* __restrict__ mach_ebf,
                                               unsigned short* __restrict__ Wb,
                                               float* __restrict__ mach_sum,
                                               int* __restrict__ desc_i) {   // lookback descs (zeroed)
    int t = threadIdx.x;
    if (blockIdx.x >= NBC) {
        // ---- prep: op embed bf16 | mach embed f32+bf16 | weight conv | zeros ----
        const int T0 = NUM_OPS * HDIM;
        const int T1 = T0 + NUM_MACH * HDIM;
        const int T2 = T1 + 2 * 128 * 256;
        const int T3 = T2 + NUM_MACH * HDIM;
        const int T4 = T3 + 2 * NBLK_T;            // desc zero (as ints)
        int stride = NB_PREP * 256;
        for (int idx = (blockIdx.x - NBC) * 256 + t; idx < T4; idx += stride) {
            if (idx < T0) {
                int r = idx >> 7, h = idx & 127;
                const float* f = Fo + (size_t)r * 6;
                const float* w = Wo + (size_t)h * 6;
                float s = bo[h];
#pragma unroll
                for (int i = 0; i < 6; ++i) s += f[i] * w[i];
                op_ebf[idx] = f2bf(s);
            } else if (idx < T1) {
                int j = idx - T0;
                int r = j >> 7, h = j & 127;
                const float* f = Fm + (size_t)r * 2;
                const float* w = Wm + (size_t)h * 2;
                float s = bm[h] + f[0] * w[0] + f[1] * w[1];
                mach_emb[j] = s;
                mach_ebf[j] = f2bf(s);
            } else if (idx < T2) {
                int j = idx - T1;
                int l = j >> 15, h = (j >> 8) & 127, k = j & 255;
                float v = (k < 128) ? Wp[(size_t)l * 16384 + h * 128 + k]
                                    : Wc[(size_t)l * 16384 + h * 128 + (k - 128)];
                Wb[j] = f2bf(v);
            } else if (idx < T3) {
                mach_sum[idx - T2] = 0.f;
            } else {
                desc_i[idx - T3] = 0;
            }
        }
        return;
    }

    __shared__ int hc[NCOARSE];
    __shared__ int hm[NUM_MACH];
    for (int i = t; i < NCOARSE; i += 256) hc[i] = 0;
    for (int i = t; i < NUM_MACH; i += 256) hm[i] = 0;
    __syncthreads();
    int NT = nprec + E;
    int ch = (NT + NBC - 1) / NBC;
    int i0 = blockIdx.x * ch, i1 = min(NT, i0 + ch);
    for (int i = i0 + t; i < i1; i += 256) {
        int key;
        if (i < nprec) key = prec_e[nprec + i];
        else {
            int e = i - nprec;
            key = P1 + comp_e[e];
            atomicAdd(&hm[comp_e[E + e] - M], 1);
        }
        atomicAdd(&hc[key >> 8], 1);
    }
    __syncthreads();
    for (int i = t; i < NCOARSE; i += 256)
        chist_bh[i * NBC + blockIdx.x] = hc[i];
    for (int i = t; i < NUM_MACH; i += 256)
        mach_bh[i * NBC + blockIdx.x] = hm[i];
}

// ---------------- single-pass scan: decoupled lookback, two segments ----------------
// Tile b scans arr[b*1024 .. +1024) and writes exclusive offsets into scans[]. Aggregate/
// inclusive published in one 64-bit word (flag in bits 62-63, value below) -> no torn reads.
// Lookback clamped at segment start (blocks < NBLK: op segment; >= NBLK: machine segment).
#define FLAG_AGG 1ULL
#define FLAG_INC 2ULL
__global__ __launch_bounds__(256) void k_scan(const int* __restrict__ arr,
                                              unsigned long long* __restrict__ desc,
                                              int* __restrict__ scans) {
    __shared__ int sh[256];
    __shared__ int s_excl;
    int b = blockIdx.x, t = threadIdx.x;
    int base_i = b * 1024 + t * 4;
    int4 v = *(const int4*)(arr + base_i);
    int tsum = v.x + v.y + v.z + v.w;
    sh[t] = tsum; __syncthreads();
    for (int o = 1; o < 256; o <<= 1) {
        int x = (t >= o) ? sh[t - o] : 0; __syncthreads();
        sh[t] += x; __syncthreads();
    }
    int total = sh[255];
    int seg_start = (b < NBLK) ? 0 : NBLK;

    if (t == 0)
        atomicExch(&desc[b], (FLAG_AGG << 62) | (unsigned long long)(unsigned)total);

    if (t < 64) {
        int excl = 0;
        int i = b - 1;
        bool done = (i < seg_start);
        while (!done) {
            int idx = i - t;
            unsigned long long flag; int val;
            if (idx >= seg_start) {
                unsigned long long dv;
                do { dv = atomicAdd(&desc[idx], 0ULL); flag = dv >> 62; } while (flag == 0);
                val = (int)(unsigned)(dv & 0xFFFFFFFFULL);
            } else { flag = FLAG_INC; val = 0; }
            unsigned long long mask = __ballot(flag == FLAG_INC);
            if (mask) {
                int low = __ffsll(mask) - 1;        // nearest predecessor with INCLUSIVE
                int contrib = (t <= low) ? val : 0;
#pragma unroll
                for (int o2 = 32; o2; o2 >>= 1) contrib += __shfl_xor(contrib, o2);
                excl += contrib;
                done = true;
            } else {
                int contrib = val;
#pragma unroll
                for (int o2 = 32; o2; o2 >>= 1) contrib += __shfl_xor(contrib, o2);
                excl += contrib;
                i -= 64;
                done = (i < seg_start);
            }
        }
        if (t == 0) {
            s_excl = excl;
            atomicExch(&desc[b], (FLAG_INC << 62) | (unsigned long long)(unsigned)(excl + total));
        }
    }
    __syncthreads();
    int off = s_excl + sh[t] - tsum;
    int4 r; r.x = off; r.y = off + v.x; r.z = off + v.x + v.y; r.w = off + v.x + v.y + v.z;
    *(int4*)(scans + base_i) = r;
}

// ---------------- coarse pass B: place packed (val<<8 | key&255) via LDS cursors ----------------
__global__ __launch_bounds__(256) void k_cfill(const int* __restrict__ prec_e, int nprec,
                                               const int* __restrict__ comp_e, int E, int M,
                                               const int* __restrict__ scan,
                                               int* __restrict__ pairs) {
    __shared__ int cur[NCOARSE];
    for (int i = threadIdx.x; i < NCOARSE; i += 256) cur[i] = scan[i * NBC + blockIdx.x];
    __syncthreads();
    int NT = nprec + E;
    int ch = (NT + NBC - 1) / NBC;
    int i0 = blockIdx.x * ch, i1 = min(NT, i0 + ch);
    for (int i = i0 + threadIdx.x; i < i1; i += 256) {
        int key, val;
        if (i < nprec) { key = prec_e[nprec + i]; val = prec_e[i]; }
        else { int e = i - nprec; key = P1 + comp_e[e]; val = comp_e[E + e] - M; }
        int pos = atomicAdd(&cur[key >> 8], 1);
        pairs[pos] = (val << 8) | (key & 255);
    }
}

// ---------------- fine counting sort (op keys) + machine placement + mach_rs, one launch -----
__global__ __launch_bounds__(256) void k_finefill(const int* __restrict__ scans, int NT,
                                                  const int* __restrict__ pairs,
                                                  int* __restrict__ rs,
                                                  int* __restrict__ bucket_all,
                                                  const int* __restrict__ comp_e, int E, int M,
                                                  int* __restrict__ bucket_mach,
                                                  int* __restrict__ mach_rs) {
    int t = threadIdx.x;
    if (blockIdx.x < NCOARSE) {
        __shared__ int hh[256];
        __shared__ int ex[256];
        __shared__ int cu[256];
        int b = blockIdx.x;
        int s = scans[b * NBC];
        int e = (b == NCOARSE - 1) ? NT : scans[(b + 1) * NBC];
        hh[t] = 0;
        __syncthreads();
        for (int i = s + t; i < e; i += 256) atomicAdd(&hh[pairs[i] & 255], 1);
        __syncthreads();
        int v = hh[t];
        ex[t] = v; __syncthreads();
        for (int o = 1; o < 256; o <<= 1) {
            int x = (t >= o) ? ex[t - o] : 0; __syncthreads();
            ex[t] += x; __syncthreads();
        }
        int start = s + ex[t] - v;
        rs[b * 256 + t] = start;
        cu[t] = start;
        __syncthreads();
        for (int i = s + t; i < e; i += 256) {
            int p = pairs[i];
            int pos = atomicAdd(&cu[p & 255], 1);
            bucket_all[pos] = ((unsigned)p) >> 8;
        }
    } else {
        __shared__ int cur[NUM_MACH];
        int blk = blockIdx.x - NCOARSE;
        const int* moff = scans + NHIST;
        for (int i = t; i < NUM_MACH; i += 256) cur[i] = moff[i * NBM + blk];
        if (blk == 0) {
            for (int m = t; m < NUM_MACH; m += 256) mach_rs[m] = moff[m * NBM];
            if (t == 0) mach_rs[NUM_MACH] = E;
        }
        __syncthreads();
        int nprec = NT - E;
        int chNT = (NT + NBC - 1) / NBC;            // SAME chunking as k_front
        int e0 = blk * chNT - nprec;       if (e0 < 0) e0 = 0;
        int e1 = (blk + 1) * chNT - nprec; if (e1 > E) e1 = E;
        for (int e = e0 + t; e < e1; e += 256) {
            int m = comp_e[E + e] - M;
            int op = comp_e[e];
            int pos = atomicAdd(&cur[m], 1);
            bucket_mach[pos] = op;
        }
    }
}

#define ACC8(acc, v) { _Pragma("unroll") for (int k = 0; k < 8; ++k) acc[k] += bf2f((unsigned short)v[k]); }

// ---------------- merged per-layer aggregation: op-side gather->Ab | machine-side gather ------
// (r13-verified configuration: op-agg blocks first, NM*4 machine blocks at the grid tail,
//  16-edge staged machine path, stride 1024)
__global__ __launch_bounds__(256) void k_aggmg(
    const unsigned short* __restrict__ op_ebf, const unsigned short* __restrict__ mach_ebf,
    const int* __restrict__ rs, const int* __restrict__ bucket_all,
    unsigned short* __restrict__ Ab, int* __restrict__ flags, int M,
    const int* __restrict__ mach_rs, const int* __restrict__ bucket_mach,
    float* __restrict__ mach_sum, int nb_agg) {
    int wave = threadIdx.x >> 6, lane = threadIdx.x & 63;
    int g = lane >> 4;               // edge sub-group 0..3
    int d = (lane & 15) * 8;         // dim base: 8 bf16 per lane

    if ((int)blockIdx.x < nb_agg) {
        // ---- op aggregation: dual-stream interleaved gather (4 loads in flight) ----
        int r = blockIdx.x * 4 + wave;
        if (r >= M) return;
        int sA = rs[r],      eA = rs[r + 1];
        int sB = rs[P1 + r], eB = rs[P1 + r + 1];

        float a[8], b[8];
#pragma unroll
        for (int k = 0; k < 8; ++k) { a[k] = 0.f; b[k] = 0.f; }

        int baseA = sA, baseB = sB;
        while (baseA < eA || baseB < eB) {
            int cA = (baseA < eA) ? min(64, eA - baseA) : 0;
            int cB = (baseB < eB) ? min(64, eB - baseB) : 0;
            int idxA = (lane < cA) ? bucket_all[baseA + lane] : 0;
            int idxB = (lane < cB) ? bucket_all[baseB + lane] : 0;
            int jm = max(cA, cB);
            for (int j = 0; j < jm; j += 8) {
                int j0 = j + g, j1 = j + 4 + g;
                int rA0 = __shfl(idxA, j0);
                int rA1 = __shfl(idxA, j1);
                int rB0 = __shfl(idxB, j0);
                int rB1 = __shfl(idxB, j1);
                short8 vA0 = *(const short8*)(op_ebf   + (size_t)rA0 * HDIM + d);
                short8 vA1 = *(const short8*)(op_ebf   + (size_t)rA1 * HDIM + d);
                short8 vB0 = *(const short8*)(mach_ebf + (size_t)rB0 * HDIM + d);
                short8 vB1 = *(const short8*)(mach_ebf + (size_t)rB1 * HDIM + d);
                if (j0 < cA) ACC8(a, vA0);
                if (j1 < cA) ACC8(a, vA1);
                if (j0 < cB) ACC8(b, vB0);
                if (j1 < cB) ACC8(b, vB1);
            }
            baseA += 64; baseB += 64;
        }
#pragma unroll
        for (int k = 0; k < 8; ++k) {
            a[k] += __shfl_xor(a[k], 16);
            a[k] += __shfl_xor(a[k], 32);
            b[k] += __shfl_xor(b[k], 16);
            b[k] += __shfl_xor(b[k], 32);
        }
        float pinv = 1.f / fmaxf((float)(eA - sA), 1.f);
        float cinv = 1.f / fmaxf((float)(eB - sB), 1.f);

        if (lane < 16) {
            ushort8 pa, pb;
#pragma unroll
            for (int k = 0; k < 8; ++k) { pa[k] = f2bf(a[k] * pinv); pb[k] = f2bf(b[k] * cinv); }
            *(ushort8*)(Ab + (size_t)r * 256 + d)       = pa;
            *(ushort8*)(Ab + (size_t)r * 256 + 128 + d) = pb;
        }
        if (lane == 0) flags[r] = (eA > sA ? 1 : 0) | (eB > sB ? 2 : 0);
        return;
    }

    // ---- machine gather: 16-edge staged batches, 16 groups/machine, stride 1024 ----
    int b2 = blockIdx.x - nb_agg;
    int m  = b2 & 511;
    int yq = b2 >> 9;                 // 0..3
    int s0 = mach_rs[m], e0 = mach_rs[m + 1];
    float a[8];
#pragma unroll
    for (int k = 0; k < 8; ++k) a[k] = 0.f;

    for (int base = s0 + (yq * 4 + wave) * 64; base < e0; base += 1024) {
        int cnt = min(64, e0 - base);
        int idx = (lane < cnt) ? bucket_mach[base + lane] : 0;
        int j = 0;
        for (; j + 16 <= cnt; j += 16) {
            int r0 = __shfl(idx, j + g);
            int r1 = __shfl(idx, j + 4 + g);
            int r2 = __shfl(idx, j + 8 + g);
            int r3 = __shfl(idx, j + 12 + g);
            short8 v0 = *(const short8*)(op_ebf + (size_t)r0 * HDIM + d);
            short8 v1 = *(const short8*)(op_ebf + (size_t)r1 * HDIM + d);
            short8 v2 = *(const short8*)(op_ebf + (size_t)r2 * HDIM + d);
            short8 v3 = *(const short8*)(op_ebf + (size_t)r3 * HDIM + d);
            ACC8(a, v0); ACC8(a, v1); ACC8(a, v2); ACC8(a, v3);
        }
        for (; j < cnt; j += 4) {
            int jj = j + g;
            int rowi = __shfl(idx, jj);
            short8 v = *(const short8*)(op_ebf + (size_t)rowi * HDIM + d);
            if (jj < cnt) ACC8(a, v);
        }
    }
#pragma unroll
    for (int k = 0; k < 8; ++k) {
        a[k] += __shfl_xor(a[k], 16);
        a[k] += __shfl_xor(a[k], 32);
    }
    if (lane < 16) {
#pragma unroll
        for (int k = 0; k < 8; ++k)
            atomicAdd(&mach_sum[m * HDIM + d + k], a[k]);
    }
}

// ---------------- MFMA GEMM + bf16 residual + LN  |  machine update (tail blocks) ------------
__global__ __launch_bounds__(256) void k_gemm_mupd(
    const unsigned short* __restrict__ Ab, const unsigned short* __restrict__ embb,
    const unsigned short* __restrict__ Wb,
    const float* __restrict__ bp, const float* __restrict__ bc,
    const int* __restrict__ flags,
    const float* __restrict__ g, const float* __restrict__ bt,
    float* __restrict__ dstf, unsigned short* __restrict__ dstb, int M, int nb_gemm,
    const float* __restrict__ mach_emb, float* __restrict__ mach_sum,
    const int* __restrict__ mach_rs,
    const float* __restrict__ Wc,
    const float* __restrict__ gm, const float* __restrict__ btm,
    float* __restrict__ mdst, unsigned short* __restrict__ mdstb) {
    if ((int)blockIdx.x >= nb_gemm) {
        // ---- machine update: mean -> @Wc^T + bc -> +emb -> LN; zero mach_sum after read ----
        __shared__ float row[HDIM];
        __shared__ float red[4];
        int m = blockIdx.x - nb_gemm, t = threadIdx.x;
        int cnt = mach_rs[m + 1] - mach_rs[m];
        float sc = (cnt > 0) ? 1.f / (float)cnt : 0.f;
        if (t < HDIM) {
            row[t] = mach_sum[m * HDIM + t] * sc;
            mach_sum[m * HDIM + t] = 0.f;      // ready for next layer's atomics
        }
        __syncthreads();
        float x = 0.f, s = 0.f, q = 0.f;
        if (t < HDIM) {
            float dot = bc[t];
            const float* w = Wc + (size_t)t * HDIM;
#pragma unroll 8
            for (int k = 0; k < HDIM; ++k) dot += row[k] * w[k];
            x = mach_emb[m * HDIM + t] + ((cnt > 0) ? dot : 0.f);
            s = x; q = x * x;
#pragma unroll
            for (int o = 32; o; o >>= 1) { s += __shfl_xor(s, o); q += __shfl_xor(q, o); }
            int wv = t >> 6;
            if ((t & 63) == 0) { red[wv * 2] = s; red[wv * 2 + 1] = q; }
        }
        __syncthreads();
        if (t < HDIM) {
            s = red[0] + red[2]; q = red[1] + red[3];
            float mu = s * (1.f / 128.f);
            float rstd = rsqrtf(fmaxf(q * (1.f / 128.f) - mu * mu, 0.f) + 1e-5f);
            float y = (x - mu) * rstd * gm[t] + btm[t];
            mdst[m * HDIM + t] = y;
            if (mdstb) mdstb[m * HDIM + t] = f2bf(y);
        }
        return;
    }

    int wave = threadIdx.x >> 6, lane = threadIdx.x & 63;
    int m0 = blockIdx.x * 64 + wave * 16;
    if (m0 >= M) return;
    int quad = lane >> 4, col = lane & 15;

    floatx4 acc[8];
#pragma unroll
    for (int t = 0; t < 8; ++t) acc[t] = (floatx4){0.f, 0.f, 0.f, 0.f};

    const short* Arow  = (const short*)(Ab + (size_t)(m0 + col) * 256);
    const short* Wbase = (const short*)Wb;

#pragma unroll
    for (int ks = 0; ks < 8; ++ks) {
        short8 a = *(const short8*)(Arow + ks * 32 + quad * 8);
#pragma unroll
        for (int t = 0; t < 8; ++t) {
            short8 b = *(const short8*)(Wbase + (size_t)(t * 16 + col) * 256 + ks * 32 + quad * 8);
            acc[t] = __builtin_amdgcn_mfma_f32_16x16x32_bf16(a, b, acc[t], 0, 0, 0);
        }
    }

    float bpv[8], bcv[8], gv[8], btv[8];
#pragma unroll
    for (int t = 0; t < 8; ++t) {
        int c = t * 16 + col;
        bpv[t] = bp[c]; bcv[t] = bc[c]; gv[t] = g[c]; btv[t] = bt[c];
    }
#pragma unroll
    for (int reg = 0; reg < 4; ++reg) {
        int r = m0 + quad * 4 + reg;
        int fl = flags[r];
        float fp = (fl & 1) ? 1.f : 0.f, fc = (fl & 2) ? 1.f : 0.f;
        float x[8]; float s = 0.f, q = 0.f;
#pragma unroll
        for (int t = 0; t < 8; ++t) {
            float v = acc[t][reg] + bf2f(embb[(size_t)r * HDIM + t * 16 + col]) + fp * bpv[t] + fc * bcv[t];
            x[t] = v; s += v; q += v * v;
        }
#pragma unroll
        for (int msk = 1; msk < 16; msk <<= 1) { s += __shfl_xor(s, msk); q += __shfl_xor(q, msk); }
        float mu = s * (1.f / 128.f);
        float rstd = rsqrtf(fmaxf(q * (1.f / 128.f) - mu * mu, 0.f) + 1e-5f);
#pragma unroll
        for (int t = 0; t < 8; ++t) {
            float y = (x[t] - mu) * rstd * gv[t] + btv[t];
            if (dstf) dstf[(size_t)r * HDIM + t * 16 + col] = y;
            if (dstb) dstb[(size_t)r * HDIM + t * 16 + col] = f2bf(y);
        }
    }
}

extern "C" void kernel_launch(void* const* d_in, const int* in_sizes, int n_in,
                              void* d_out, int out_size, void* d_ws, size_t ws_size,
                              hipStream_t stream) {
    const float* op_feat    = (const float*)d_in[0];
    const float* m_feat     = (const float*)d_in[1];
    const int*   prec_e     = (const int*)d_in[2];
    const int*   comp_e     = (const int*)d_in[3];
    const float* op_emb_W   = (const float*)d_in[4];
    const float* op_emb_b   = (const float*)d_in[5];
    const float* mach_emb_W = (const float*)d_in[6];
    const float* mach_emb_b = (const float*)d_in[7];
    const float* prec_W     = (const float*)d_in[8];
    const float* prec_b     = (const float*)d_in[9];
    const float* compat_W   = (const float*)d_in[10];
    const float* compat_b   = (const float*)d_in[11];
    const float* op_ln_g    = (const float*)d_in[12];
    const float* op_ln_b    = (const float*)d_in[13];
    const float* mach_ln_g  = (const float*)d_in[14];
    const float* mach_ln_b  = (const float*)d_in[15];
    float* out = (float*)d_out;

    const int M = NUM_OPS, NM = NUM_MACH;
    const int nprec = in_sizes[2] / 2;
    const int ncomp = in_sizes[3] / 2;
    const int E = ncomp / 2;   // bidirectional pairs: first half o2m, second half m2o (mirror)
    const int NT = nprec + E;

    float* ws = (float*)d_ws;
    size_t o = 0;
    unsigned short* op_ebf = (unsigned short*)(ws + o); o += (size_t)M * 64;   // 25.6 MB bf16 state
    unsigned short* Ab = (unsigned short*)(ws + o); o += (size_t)M * 128;  // 51 MB bf16 [M][256]
    unsigned short* Wb = (unsigned short*)(ws + o); o += 32768;            // 2 layers x [128][256] bf16
    float* mach_emb = ws + o; o += (size_t)NM * HDIM;
    unsigned short* mach_ebf = (unsigned short*)(ws + o); o += (size_t)NM * 64;
    float* mach_sum = ws + o; o += (size_t)NM * HDIM;
    int* ip = (int*)(ws + o);
    size_t io = 0;
    int* hists     = ip + io; io += NHIST + MHWORDS;  // [chist 784x256 | mach_bh 512x256]
    int* scans     = ip + io; io += NHIST + MHWORDS;  // [cscan | moff] (exclusive offsets)
    int* rs        = ip + io; io += NHIST;            // fine row starts (exclusive)
    int* mach_rs   = ip + io; io += NM + 8;
    unsigned long long* desc = (unsigned long long*)(ip + io); io += 1024;  // lookback descs
    int* flags     = ip + io; io += M;
    int* pairs     = ip + io; io += (size_t)NT;       // coarse-partitioned packed edges
    int* bucket_all  = ip + io; io += (size_t)NT;
    int* bucket_mach = ip + io; io += (size_t)E;

    int* mach_bh = hists + NHIST;

    // ---- CSR build + prep: front/prep merged, single-pass scan, 4 launches total ----
    k_front<<<NBC + NB_PREP, 256, 0, stream>>>(prec_e, nprec, comp_e, E, M, hists, mach_bh,
                                               op_feat, m_feat, op_emb_W, op_emb_b,
                                               mach_emb_W, mach_emb_b, prec_W, compat_W,
                                               op_ebf, mach_emb, mach_ebf, Wb, mach_sum,
                                               (int*)desc);
    k_scan<<<NBLK_T, 256, 0, stream>>>(hists, desc, scans);
    k_cfill<<<NBC, 256, 0, stream>>>(prec_e, nprec, comp_e, E, M, scans, pairs);
    k_finefill<<<NCOARSE + NBM, 256, 0, stream>>>(scans, NT, pairs, rs, bucket_all,
                                                  comp_e, E, M, bucket_mach, mach_rs);

    const int nb_agg = (M + 3) / 4;      // 1 row per wave, 4 waves per block (r9 config)
    const int nb_gemm = (M + 63) / 64;
    for (int l = 0; l < 2; ++l) {
        int last = (l == 1);
        const float* bpl = prec_b   + (size_t)l * HDIM;
        const float* Wc  = compat_W + (size_t)l * HDIM * HDIM;
        const float* bcl = compat_b + (size_t)l * HDIM;

        // merged: op-side aggregation (writes Ab/flags) + machine-side gather (atomics mach_sum)
        k_aggmg<<<nb_agg + NM * 4, 256, 0, stream>>>(
            op_ebf, mach_ebf, rs, bucket_all, Ab, flags, M,
            mach_rs, bucket_mach, mach_sum, nb_agg);

        // merged: op update (MFMA+LN, in-place bf16 state) + machine update (zeroes mach_sum)
        k_gemm_mupd<<<nb_gemm + NM, 256, 0, stream>>>(
            Ab, op_ebf, Wb + (size_t)l * 128 * 256, bpl, bcl, flags,
            op_ln_g + (size_t)l * HDIM, op_ln_b + (size_t)l * HDIM,
            last ? out : nullptr, last ? nullptr : op_ebf, M, nb_gemm,
            mach_emb, mach_sum, mach_rs, Wc,
            mach_ln_g + (size_t)l * HDIM, mach_ln_b + (size_t)l * HDIM,
            last ? (out + (size_t)M * HDIM) : mach_emb, last ? nullptr : mach_ebf);
    }
}